// Round 2
// baseline (5356.323 us; speedup 1.0000x reference)
//
#include <hip/hip_runtime.h>
#include <math.h>

// ---------------- constants ----------------
constexpr int Bn = 256;    // batch
constexpr int Ln = 200;    // seq len
constexpr int Dn = 128;    // node dim
constexpr int Hn = 128;    // AUGRU hidden
constexpr int C0 = 80;     // attn fc0 width
constexpr int C1 = 40;     // attn fc1 width
constexpr int T0 = 200;    // task fc0 width
constexpr int T1 = 80;     // task fc1 width
constexpr int POOLN = 30;
constexpr float EPS = 1e-4f;
constexpr float NEGINF = -1e30f;
constexpr float NEGBIG = -4294967295.0f;

__device__ __forceinline__ float lrelu(float x) { return x > 0.f ? x : 0.01f * x; }
__device__ __forceinline__ float sigmoidf(float x) { return 1.f / (1.f + expf(-x)); }

// ---------------- build X, tgt, mask ----------------
__global__ void build_x_kernel(const int* his_pro, const int* his_y,
                               const float* item_emb, const float* ans_emb, float* X) {
    int l = blockIdx.x, b = blockIdx.y, t = threadIdx.x; // 128 threads
    size_t row = ((size_t)b * Ln + l) * Dn;
    if (t < 64) X[row + t] = item_emb[(size_t)his_pro[b * Ln + l] * 64 + t];
    else        X[row + t] = ans_emb[his_y[b * Ln + l] * 64 + (t - 64)];
}

__global__ void build_tgt_mask_kernel(const int* cur_pro, const int* his_len,
                                      const float* item_emb, float* tgt, float* mask) {
    int b = blockIdx.x, t = threadIdx.x; // 256 threads
    if (t < 64) tgt[b * Dn + t] = item_emb[(size_t)cur_pro[b] * 64 + t];
    else if (t < 128) tgt[b * Dn + t] = 0.f;
    if (t < Ln) mask[b * Ln + t] = (t < his_len[b]) ? 1.f : 0.f;
}

// ---------------- Xf = normalize(X * w) ----------------
__global__ void xf_kernel(const float* X, const float* wt, float* Xf) {
    int l = blockIdx.x, b = blockIdx.y, t = threadIdx.x; // 128
    __shared__ float red[128];
    size_t row = ((size_t)b * Ln + l) * Dn;
    float v = X[row + t] * wt[t];
    red[t] = v * v;
    __syncthreads();
    for (int s = 64; s > 0; s >>= 1) { if (t < s) red[t] += red[t + s]; __syncthreads(); }
    float norm = fmaxf(sqrtf(red[0]), 1e-12f);
    Xf[row + t] = v / norm;
}

// ---------------- S row: dot, min-max scale, mask, count ----------------
__global__ void s_kernel(const float* Xf, const float* mask, float* S, int* nedges) {
    int l = blockIdx.x, b = blockIdx.y, t = threadIdx.x; // 128
    __shared__ float xr[Dn];
    __shared__ float row[Ln];
    __shared__ float red[128];
    xr[t] = Xf[((size_t)b * Ln + l) * Dn + t];
    __syncthreads();
    for (int m = t; m < Ln; m += 128) {
        const float* xm = Xf + ((size_t)b * Ln + m) * Dn;
        float acc = 0.f;
        for (int d = 0; d < Dn; ++d) acc += xr[d] * xm[d];
        row[m] = acc;
    }
    __syncthreads();
    float mn = 3.4e38f, mx = -3.4e38f;
    for (int m = t; m < Ln; m += 128) { mn = fminf(mn, row[m]); mx = fmaxf(mx, row[m]); }
    red[t] = mn; __syncthreads();
    for (int s = 64; s > 0; s >>= 1) { if (t < s) red[t] = fminf(red[t], red[t + s]); __syncthreads(); }
    mn = red[0]; __syncthreads();
    red[t] = mx; __syncthreads();
    for (int s = 64; s > 0; s >>= 1) { if (t < s) red[t] = fmaxf(red[t], red[t + s]); __syncthreads(); }
    mx = red[0]; __syncthreads();
    float denom = mx - mn;
    float ml = mask[b * Ln + l];
    int cnt = 0;
    for (int m = t; m < Ln; m += 128) {
        float v = (denom > 0.f) ? (row[m] - mn) / denom : 0.f; // nan_to_num(0/0)=0
        v *= ml * mask[b * Ln + m];
        S[((size_t)b * Ln + l) * Ln + m] = v;
        cnt += (v != 0.f);
    }
    red[t] = (float)cnt; __syncthreads();
    for (int s = 64; s > 0; s >>= 1) { if (t < s) red[t] += red[t + s]; __syncthreads(); }
    if (t == 0) atomicAdd(&nedges[b], (int)red[0]);
}

// ---------------- exact k-th largest (descending index k) via radix select ----------------
__global__ void radix_select_kernel(const float* S, const int* nedges, float* thrA) {
    int b = blockIdx.x, t = threadIdx.x; // 256
    __shared__ unsigned int hist[256];
    __shared__ unsigned int prefix;
    __shared__ int kk;
    const unsigned int* data = (const unsigned int*)(S + (size_t)b * Ln * Ln);
    if (t == 0) { prefix = 0u; kk = (nedges[b] + 1) >> 1; } // ceil(n*0.5)
    __syncthreads();
    for (int pass = 0; pass < 4; ++pass) {
        int shift = 24 - 8 * pass;
        hist[t] = 0u;
        __syncthreads();
        unsigned int pmask = (pass == 0) ? 0u : (0xFFFFFFFFu << (shift + 8));
        unsigned int pref = prefix;
        for (int i = t; i < Ln * Ln; i += 256) {
            unsigned int x = data[i];
            if ((x & pmask) == pref) atomicAdd(&hist[(x >> shift) & 255u], 1u);
        }
        __syncthreads();
        if (t == 0) {
            int k = kk;
            for (int bin = 255; bin >= 0; --bin) {
                int c = (int)hist[bin];
                if (k < c) { prefix = pref | ((unsigned int)bin << shift); break; }
                k -= c;
            }
            kk = k;
        }
        __syncthreads();
    }
    if (t == 0) thrA[b] = __uint_as_float(prefix);
}

// ---------------- degree -> dis = rsqrt(deg) ----------------
__global__ void deg_kernel(const float* S, const float* thrA, float* dis) {
    int l = blockIdx.x, b = blockIdx.y, t = threadIdx.x; // 64
    __shared__ float red[64];
    float thr = thrA[b];
    const float* row = S + ((size_t)b * Ln + l) * Ln;
    int cnt = 0;
    for (int m = t; m < Ln; m += 64) if (m != l && row[m] > thr) cnt++;
    red[t] = (float)cnt; __syncthreads();
    for (int s = 32; s > 0; s >>= 1) { if (t < s) red[t] += red[t + s]; __syncthreads(); }
    if (t == 0) dis[b * Ln + l] = rsqrtf(red[0] + 1.f); // +1 self loop
}

// ---------------- An = A_bool * dis_l * dis_m (in-place over S) ----------------
__global__ void an_kernel(float* S, const float* thrA, const float* dis) {
    size_t idx = (size_t)blockIdx.x * 256 + threadIdx.x;
    if (idx >= (size_t)Bn * Ln * Ln) return;
    int b = (int)(idx / (Ln * Ln));
    int rem = (int)(idx % (Ln * Ln));
    int l = rem / Ln, m = rem % Ln;
    float ab = (l == m) ? 1.f : ((S[idx] > thrA[b]) ? 1.f : 0.f);
    S[idx] = ab * dis[b * Ln + l] * dis[b * Ln + m];
}

// ---------------- C[b,l,:] = sum_m An[b,l,m] * M[b,m,:] ----------------
__global__ void an_matmul_kernel(const float* An, const float* M, float* C) {
    int l = blockIdx.x, b = blockIdx.y, t = threadIdx.x; // 128
    const float* Arow = An + ((size_t)b * Ln + l) * Ln;
    const float* Mb = M + (size_t)b * Ln * Dn;
    float acc = 0.f;
    for (int m = 0; m < Ln; ++m) acc += Arow[m] * Mb[m * Dn + t];
    C[((size_t)b * Ln + l) * Dn + t] = acc;
}

// ---------------- attention FCN pieces ----------------
__global__ void ai_kernel(const float* kv, const float* mat, float* ai) {
    int l = blockIdx.x, b = blockIdx.y, t = threadIdx.x; // 128
    size_t row = (size_t)b * Ln + l;
    __shared__ float x[Dn];
    x[t] = kv[row * Dn + t];
    __syncthreads();
    float acc = 0.f;
    for (int k = 0; k < Dn; ++k) acc += x[k] * mat[k * Dn + t];
    ai[row * Dn + t] = acc;
}

__global__ void attn_fc0_kernel(const float* ai, const float* query, int q3d,
                                const float* w0, const float* b0, float* z0) {
    int l = blockIdx.x, b = blockIdx.y, t = threadIdx.x; // 128
    size_t row = (size_t)b * Ln + l;
    __shared__ float sa[Dn], sq[Dn];
    sa[t] = ai[row * Dn + t];
    sq[t] = q3d ? query[row * Dn + t] : query[(size_t)b * Dn + t];
    __syncthreads();
    if (t < C0) {
        float acc = b0[t];
        for (int k = 0; k < Dn; ++k) {
            float a = sa[k], q = sq[k];
            acc += a * w0[k * C0 + t];
            acc += q * w0[(Dn + k) * C0 + t];
            acc += (a - q) * w0[(2 * Dn + k) * C0 + t];
            acc += (a * q) * w0[(3 * Dn + k) * C0 + t];
        }
        z0[row * C0 + t] = acc;
    }
}

// stats[c] = sum, stats[C+c] = sumsq.  blockDim=(C,TY)
__global__ void bn_stats_kernel(const float* z, int N, int C, float* stats) {
    int c = threadIdx.x;
    extern __shared__ float red[]; // 2*C*TY
    float s = 0.f, q = 0.f;
    for (int r = blockIdx.x * blockDim.y + threadIdx.y; r < N; r += gridDim.x * blockDim.y) {
        float v = z[(size_t)r * C + c];
        s += v; q += v * v;
    }
    red[threadIdx.y * C + c] = s;
    red[blockDim.y * C + threadIdx.y * C + c] = q;
    __syncthreads();
    if (threadIdx.y == 0) {
        for (int ty = 1; ty < (int)blockDim.y; ++ty) {
            s += red[ty * C + c];
            q += red[blockDim.y * C + ty * C + c];
        }
        atomicAdd(&stats[c], s);
        atomicAdd(&stats[C + c], q);
    }
}

__global__ void attn_fc1_kernel(const float* z0, const float* stats0, const float* g0, const float* be0,
                                const float* w1, const float* b1, float* z1, int N) {
    int l = blockIdx.x, b = blockIdx.y, t = threadIdx.x; // 128
    size_t row = (size_t)b * Ln + l;
    __shared__ float y[C0];
    if (t < C0) {
        float mean = stats0[t] / N;
        float var = stats0[C0 + t] / N - mean * mean;
        float v = (z0[row * C0 + t] - mean) * rsqrtf(var + EPS) * g0[t] + be0[t];
        y[t] = fmaxf(v, 0.f);
    }
    __syncthreads();
    if (t < C1) {
        float acc = b1[t];
        for (int k = 0; k < C0; ++k) acc += y[k] * w1[k * C1 + t];
        z1[row * C1 + t] = acc;
    }
}

__global__ void attn_out_kernel(const float* z1, const float* stats1, const float* g1, const float* be1,
                                const float* wo, const float* bo, float* o, int N) {
    int row = blockIdx.x * blockDim.x + threadIdx.x;
    if (row >= Bn * Ln) return;
    float acc = bo[0];
    for (int k = 0; k < C1; ++k) {
        float mean = stats1[k] / N;
        float var = stats1[C1 + k] / N - mean * mean;
        float v = (z1[(size_t)row * C1 + k] - mean) * rsqrtf(var + EPS) * g1[k] + be1[k];
        acc += fmaxf(v, 0.f) * wo[k];
    }
    o[row] = acc;
}

// softmax over L with mask; optional second addend; optional *mask on output
__global__ void masked_softmax_kernel(const float* o, const float* o2, const float* mask,
                                      float neg, int mulmask, float* w) {
    int b = blockIdx.x, t = threadIdx.x; // 256
    __shared__ float buf[Ln];
    __shared__ float red[256];
    if (t < Ln) {
        float x = o[b * Ln + t];
        if (o2) x += o2[b * Ln + t];
        buf[t] = (mask[b * Ln + t] > 0.f) ? x : neg;
    }
    __syncthreads();
    red[t] = (t < Ln) ? buf[t] : -3.4e38f;
    __syncthreads();
    for (int s = 128; s > 0; s >>= 1) { if (t < s) red[t] = fmaxf(red[t], red[t + s]); __syncthreads(); }
    float mx = red[0];
    __syncthreads();
    float e = 0.f;
    if (t < Ln) e = expf(buf[t] - mx);
    red[t] = e;
    __syncthreads();
    for (int s = 128; s > 0; s >>= 1) { if (t < s) red[t] += red[t + s]; __syncthreads(); }
    float sm = red[0];
    if (t < Ln) {
        float v = e / sm;
        if (mulmask) v *= mask[b * Ln + t];
        w[b * Ln + t] = v;
    }
}

// ---------------- E row softmax + aggregation + Xc ----------------
__global__ void fuse_xc_kernel(const float* An, const float* f1, const float* f2,
                               const float* X, const float* aggW, float* Xc) {
    int l = blockIdx.x, b = blockIdx.y, t = threadIdx.x; // 128
    __shared__ float p[Ln];
    __shared__ float red[128];
    __shared__ float ex[Dn];
    const float f2l = f2[b * Ln + l];
    float mx = -3.4e38f;
    for (int m = t; m < Ln; m += 128) {
        float ab = An[((size_t)b * Ln + l) * Ln + m]; // >0 iff A_bool
        float e;
        if (ab > 0.f) {
            e = f1[b * Ln + m] + f2l;
            e = lrelu(e);
        } else e = NEGINF;
        p[m] = e;
        mx = fmaxf(mx, e);
    }
    red[t] = mx; __syncthreads();
    for (int s = 64; s > 0; s >>= 1) { if (t < s) red[t] = fmaxf(red[t], red[t + s]); __syncthreads(); }
    mx = red[0]; __syncthreads();
    float sm = 0.f;
    for (int m = t; m < Ln; m += 128) { float e = expf(p[m] - mx); p[m] = e; sm += e; }
    red[t] = sm; __syncthreads();
    for (int s = 64; s > 0; s >>= 1) { if (t < s) red[t] += red[t + s]; __syncthreads(); }
    sm = red[0]; __syncthreads();
    float inv = 1.f / sm;
    float acc = 0.f;
    for (int m = 0; m < Ln; ++m) acc += p[m] * X[((size_t)b * Ln + m) * Dn + t];
    ex[t] = acc * inv;
    __syncthreads();
    float xo = X[((size_t)b * Ln + l) * Dn + t];
    float a2 = xo;
    for (int k = 0; k < Dn; ++k) a2 += ex[k] * aggW[k * Dn + t];
    Xc[((size_t)b * Ln + l) * Dn + t] = lrelu(a2);
}

// ---------------- pooling: mask2 = cs > (31st largest), order, red_len ----------------
__global__ void pool_kernel(const float* cs, const int* his_len, float* mask2,
                            int* order, int* red_len) {
    int b = blockIdx.x, t = threadIdx.x; // 256
    __shared__ float v[Ln];
    __shared__ float thr;
    if (t < Ln) v[t] = cs[b * Ln + t];
    __syncthreads();
    int k = min(his_len[b], POOLN);
    if (t < Ln) {
        float x = v[t];
        int gt = 0, eq = 0;
        for (int i = 0; i < Ln; ++i) { gt += (v[i] > x); eq += (v[i] == x); }
        if (gt <= k && k < gt + eq) thr = x; // the k-th order statistic (desc)
    }
    __syncthreads();
    if (t < Ln) mask2[b * Ln + t] = (v[t] > thr) ? 1.f : 0.f;
    __syncthreads();
    if (t == 0) {
        int idx = 0;
        for (int l = 0; l < Ln; ++l) if (v[l] > thr) order[b * Ln + idx++] = l;
        red_len[b] = idx;
        for (int l = 0; l < Ln; ++l) if (!(v[l] > thr)) order[b * Ln + idx++] = l;
    }
}

__global__ void readout_kernel(const float* Xc, const float* cs, const float* mask2, float* gr) {
    int b = blockIdx.x, t = threadIdx.x; // 128
    float acc = 0.f;
    for (int l = 0; l < Ln; ++l)
        acc += Xc[((size_t)b * Ln + l) * Dn + t] * cs[b * Ln + l] * mask2[b * Ln + l];
    gr[b * Dn + t] = acc;
}

__global__ void gather_kernel(const float* Xc, const float* mask2, const int* order,
                              float* Xs, float* mask_s) {
    int i = blockIdx.x, b = blockIdx.y, t = threadIdx.x; // 128
    int src = order[b * Ln + i];
    Xs[((size_t)b * Ln + i) * Dn + t] = Xc[((size_t)b * Ln + src) * Dn + t];
    if (t == 0) mask_s[b * Ln + i] = mask2[b * Ln + src];
}

// ---------------- AUGRU ----------------
__global__ void xp_kernel(const float* Xs, const float* Wx, const float* bx, float* xp) {
    int l = blockIdx.x, b = blockIdx.y, t = threadIdx.x; // 384
    __shared__ float x[Dn];
    if (t < Dn) x[t] = Xs[((size_t)b * Ln + l) * Dn + t];
    __syncthreads();
    float acc = bx[t];
    for (int d = 0; d < Dn; ++d) acc += x[d] * Wx[d * 384 + t];
    xp[((size_t)b * POOLN + l) * 384 + t] = acc;
}

__global__ void augru_kernel(const float* xp, const float* alphas, const int* red_len,
                             const float* Wh, const float* bh, float* final_h) {
    int b = blockIdx.x, j = threadIdx.x; // 128
    __shared__ float h[Hn];
    h[j] = 0.f;
    __syncthreads();
    int T = red_len[b];
    for (int step = 0; step < T; ++step) {
        float hr = bh[j], hu = bh[Hn + j], hn = bh[2 * Hn + j];
        for (int k = 0; k < Hn; ++k) {
            float hk = h[k];
            hr += hk * Wh[k * 384 + j];
            hu += hk * Wh[k * 384 + Hn + j];
            hn += hk * Wh[k * 384 + 2 * Hn + j];
        }
        const float* xrow = xp + ((size_t)b * POOLN + step) * 384;
        float a = alphas[b * Ln + step];
        float r = sigmoidf(xrow[j] + hr);
        float u = sigmoidf(xrow[Hn + j] + hu) * a;
        float n = tanhf(xrow[2 * Hn + j] + r * hn);
        float hnew = (1.f - u) * h[j] + u * n;
        __syncthreads();
        h[j] = hnew;
        __syncthreads();
    }
    final_h[b * Hn + j] = h[j];
}

// ---------------- head ----------------
__global__ void mo_kernel(const float* final_h, const float* gr, const float* tgt, float* mo) {
    int b = blockIdx.x, t = threadIdx.x; // 128
    mo[b * 512 + t] = final_h[b * Hn + t];
    mo[b * 512 + 128 + t] = gr[b * Dn + t];
    mo[b * 512 + 256 + t] = tgt[b * Dn + t];
    mo[b * 512 + 384 + t] = gr[b * Dn + t] * tgt[b * Dn + t];
}

// generic dense layer: optional BN+relu on input, then y = in' @ w + bias
__global__ void head_fc_kernel(const float* in, int K, int C, const float* w, const float* bias,
                               const float* stats, int statN, const float* g, const float* be,
                               float* out) {
    int b = blockIdx.x;
    extern __shared__ float y[]; // K floats
    for (int k = threadIdx.x; k < K; k += blockDim.x) {
        float v = in[(size_t)b * K + k];
        if (stats) {
            float mean = stats[k] / statN;
            float var = stats[K + k] / statN - mean * mean;
            v = fmaxf((v - mean) * rsqrtf(var + EPS) * g[k] + be[k], 0.f);
        }
        y[k] = v;
    }
    __syncthreads();
    for (int c = threadIdx.x; c < C; c += blockDim.x) {
        float acc = bias[c];
        for (int k = 0; k < K; ++k) acc += y[k] * w[k * C + c];
        out[(size_t)b * C + c] = acc;
    }
}

// ---------------- host driver ----------------
static void run_attn_fcn(hipStream_t stream, const float* kv, const float* query, int q3d,
                         const float* mat, const float* mask,
                         const float* w0, const float* b0, const float* g0, const float* be0,
                         const float* w1, const float* b1, const float* g1, const float* be1,
                         const float* wo, const float* bo,
                         float* ai, float* z0, float* z1, float* o,
                         float* stats0, float* stats1, float* out_w) {
    dim3 gLB(Ln, Bn);
    ai_kernel<<<gLB, 128, 0, stream>>>(kv, mat, ai);
    attn_fc0_kernel<<<gLB, 128, 0, stream>>>(ai, query, q3d, w0, b0, z0);
    hipMemsetAsync(stats0, 0, 2 * C0 * sizeof(float), stream);
    bn_stats_kernel<<<128, dim3(C0, 3), 2 * C0 * 3 * sizeof(float), stream>>>(z0, Bn * Ln, C0, stats0);
    attn_fc1_kernel<<<gLB, 128, 0, stream>>>(z0, stats0, g0, be0, w1, b1, z1, Bn * Ln);
    hipMemsetAsync(stats1, 0, 2 * C1 * sizeof(float), stream);
    bn_stats_kernel<<<128, dim3(C1, 6), 2 * C1 * 6 * sizeof(float), stream>>>(z1, Bn * Ln, C1, stats1);
    attn_out_kernel<<<(Bn * Ln + 255) / 256, 256, 0, stream>>>(z1, stats1, g1, be1, wo, bo, o, Bn * Ln);
    masked_softmax_kernel<<<Bn, 256, 0, stream>>>(o, nullptr, mask, NEGINF, 0, out_w);
}

extern "C" void kernel_launch(void* const* d_in, const int* in_sizes, int n_in,
                              void* d_out, int out_size, void* d_ws, size_t ws_size,
                              hipStream_t stream) {
    (void)in_sizes; (void)n_in; (void)out_size; (void)ws_size;
    const int* his_pro = (const int*)d_in[0];
    const int* his_y   = (const int*)d_in[1];
    const int* his_len = (const int*)d_in[2];
    const int* cur_pro = (const int*)d_in[3];
    const float* item_emb    = (const float*)d_in[5];
    const float* ans_emb     = (const float*)d_in[6];
    const float* wt          = (const float*)d_in[7];
    const float* att_cluster = (const float*)d_in[8];
    const float* att_query   = (const float*)d_in[9];
    const float* att_rnn     = (const float*)d_in[10];
    const float* aggre_W     = (const float*)d_in[11];
    const float* gru_Wx = (const float*)d_in[12];
    const float* gru_Wh = (const float*)d_in[13];
    const float* gru_bx = (const float*)d_in[14];
    const float* gru_bh = (const float*)d_in[15];
    const float* a_w0 = (const float*)d_in[16];
    const float* a_b0 = (const float*)d_in[17];
    const float* a_g0 = (const float*)d_in[18];
    const float* a_be0 = (const float*)d_in[19];
    const float* a_w1 = (const float*)d_in[20];
    const float* a_b1 = (const float*)d_in[21];
    const float* a_g1 = (const float*)d_in[22];
    const float* a_be1 = (const float*)d_in[23];
    const float* a_wo = (const float*)d_in[24];
    const float* a_bo = (const float*)d_in[25];
    const float* t_w0 = (const float*)d_in[26];
    const float* t_b0 = (const float*)d_in[27];
    const float* t_g0 = (const float*)d_in[28];
    const float* t_be0 = (const float*)d_in[29];
    const float* t_w1 = (const float*)d_in[30];
    const float* t_b1 = (const float*)d_in[31];
    const float* t_g1 = (const float*)d_in[32];
    const float* t_be1 = (const float*)d_in[33];
    const float* t_wo = (const float*)d_in[34];
    const float* t_bo = (const float*)d_in[35];

    // -------- workspace carve (~190 MB) --------
    char* p = (char*)d_ws;
    auto alloc = [&](size_t bytes) -> void* {
        void* r = (void*)p;
        p += ((bytes + 255) / 256) * 256;
        return r;
    };
    const size_t NX = (size_t)Bn * Ln * Dn;
    const size_t NS = (size_t)Bn * Ln * Ln;
    float* X    = (float*)alloc(NX * 4);
    float* XfXc = (float*)alloc(NX * 4);   // Xf, later reused as Xc
    float* S    = (float*)alloc(NS * 4);   // S, then An in-place
    float* tmp  = (float*)alloc(NX * 4);   // An@M temp, later attn 'ai'
    float* XqXs = (float*)alloc(NX * 4);   // Xq, later Xs
    float* z0   = (float*)alloc((size_t)Bn * Ln * C0 * 4);
    float* z1   = (float*)alloc((size_t)Bn * Ln * C1 * 4);
    float* obuf = (float*)alloc((size_t)Bn * Ln * 4);
    float* f1   = (float*)alloc((size_t)Bn * Ln * 4);
    float* f2   = (float*)alloc((size_t)Bn * Ln * 4);
    float* alph = (float*)alloc((size_t)Bn * Ln * 4);
    float* mask = (float*)alloc((size_t)Bn * Ln * 4);
    float* tgt  = (float*)alloc((size_t)Bn * Dn * 4);
    float* dis  = (float*)alloc((size_t)Bn * Ln * 4);
    float* thrA = (float*)alloc((size_t)Bn * 4);
    int*   nedges = (int*)alloc((size_t)Bn * 4);
    float* statsA = (float*)alloc(2 * 200 * 4);
    float* statsB = (float*)alloc(2 * 200 * 4);
    float* cs     = (float*)alloc((size_t)Bn * Ln * 4);
    float* mask2  = (float*)alloc((size_t)Bn * Ln * 4);
    int*   order  = (int*)alloc((size_t)Bn * Ln * 4);
    int*   redlen = (int*)alloc((size_t)Bn * 4);
    float* mask_s = (float*)alloc((size_t)Bn * Ln * 4);
    float* xp     = (float*)alloc((size_t)Bn * POOLN * 384 * 4);
    float* finalh = (float*)alloc((size_t)Bn * Hn * 4);
    float* gr     = (float*)alloc((size_t)Bn * Dn * 4);
    float* mo     = (float*)alloc((size_t)Bn * 512 * 4);
    float* t0buf  = (float*)alloc((size_t)Bn * T0 * 4);
    float* t1buf  = (float*)alloc((size_t)Bn * T1 * 4);

    dim3 gLB(Ln, Bn);

    // ---- inputs ----
    build_x_kernel<<<gLB, 128, 0, stream>>>(his_pro, his_y, item_emb, ans_emb, X);
    build_tgt_mask_kernel<<<Bn, 256, 0, stream>>>(cur_pro, his_len, item_emb, tgt, mask);

    // ---- similarity graph ----
    xf_kernel<<<gLB, 128, 0, stream>>>(X, wt, XfXc);
    hipMemsetAsync(nedges, 0, Bn * sizeof(int), stream);
    s_kernel<<<gLB, 128, 0, stream>>>(XfXc, mask, S, nedges);
    radix_select_kernel<<<Bn, 256, 0, stream>>>(S, nedges, thrA);
    deg_kernel<<<gLB, 64, 0, stream>>>(S, thrA, dis);
    an_kernel<<<(int)((NS + 255) / 256), 256, 0, stream>>>(S, thrA, dis); // S -> An

    // ---- fusion round 1 ----
    an_matmul_kernel<<<gLB, 128, 0, stream>>>(S, X, tmp);
    an_matmul_kernel<<<gLB, 128, 0, stream>>>(S, tmp, XqXs); // Xq
    run_attn_fcn(stream, X, XqXs, 1, att_cluster, mask,
                 a_w0, a_b0, a_g0, a_be0, a_w1, a_b1, a_g1, a_be1, a_wo, a_bo,
                 tmp, z0, z1, obuf, statsA, statsB, f1);
    run_attn_fcn(stream, X, tgt, 0, att_query, mask,
                 a_w0, a_b0, a_g0, a_be0, a_w1, a_b1, a_g1, a_be1, a_wo, a_bo,
                 tmp, z0, z1, obuf, statsA, statsB, f2);
    fuse_xc_kernel<<<gLB, 128, 0, stream>>>(S, f1, f2, X, aggre_W, XfXc); // Xc

    // ---- fusion round 2 (extraction) ----
    an_matmul_kernel<<<gLB, 128, 0, stream>>>(S, XfXc, tmp);
    an_matmul_kernel<<<gLB, 128, 0, stream>>>(S, tmp, XqXs); // Xq2
    run_attn_fcn(stream, XfXc, XqXs, 1, att_cluster, mask,
                 a_w0, a_b0, a_g0, a_be0, a_w1, a_b1, a_g1, a_be1, a_wo, a_bo,
                 tmp, z0, z1, obuf, statsA, statsB, f1);
    run_attn_fcn(stream, XfXc, tgt, 0, att_query, mask,
                 a_w0, a_b0, a_g0, a_be0, a_w1, a_b1, a_g1, a_be1, a_wo, a_bo,
                 tmp, z0, z1, obuf, statsA, statsB, f2);
    masked_softmax_kernel<<<Bn, 256, 0, stream>>>(f1, f2, mask, NEGBIG, 1, cs);

    // ---- pooling ----
    pool_kernel<<<Bn, 256, 0, stream>>>(cs, his_len, mask2, order, redlen);
    readout_kernel<<<Bn, 128, 0, stream>>>(XfXc, cs, mask2, gr);
    gather_kernel<<<gLB, 128, 0, stream>>>(XfXc, mask2, order, XqXs, mask_s); // Xs

    // ---- AUGRU ----
    run_attn_fcn(stream, XqXs, tgt, 0, att_rnn, mask_s,
                 a_w0, a_b0, a_g0, a_be0, a_w1, a_b1, a_g1, a_be1, a_wo, a_bo,
                 tmp, z0, z1, obuf, statsA, statsB, alph);
    xp_kernel<<<dim3(POOLN, Bn), 384, 0, stream>>>(XqXs, gru_Wx, gru_bx, xp);
    augru_kernel<<<Bn, 128, 0, stream>>>(xp, alph, redlen, gru_Wh, gru_bh, finalh);

    // ---- head ----
    mo_kernel<<<Bn, 128, 0, stream>>>(finalh, gr, tgt, mo);
    head_fc_kernel<<<Bn, 256, 512 * 4, stream>>>(mo, 512, T0, t_w0, t_b0,
                                                 nullptr, 0, nullptr, nullptr, t0buf);
    hipMemsetAsync(statsA, 0, 2 * T0 * sizeof(float), stream);
    bn_stats_kernel<<<32, dim3(T0, 1), 2 * T0 * sizeof(float), stream>>>(t0buf, Bn, T0, statsA);
    head_fc_kernel<<<Bn, 256, T0 * 4, stream>>>(t0buf, T0, T1, t_w1, t_b1,
                                                statsA, Bn, t_g0, t_be0, t1buf);
    hipMemsetAsync(statsB, 0, 2 * T1 * sizeof(float), stream);
    bn_stats_kernel<<<16, dim3(T1, 3), 2 * T1 * 3 * sizeof(float), stream>>>(t1buf, Bn, T1, statsB);
    head_fc_kernel<<<Bn, 256, T1 * 4, stream>>>(t1buf, T1, 1, t_wo, t_bo,
                                                statsB, Bn, t_g1, t_be1, (float*)d_out);
}

// Round 8
// 2883.005 us; speedup vs baseline: 1.8579x; 1.8579x over previous
//
#include <hip/hip_runtime.h>
#include <math.h>

// ---------------- constants ----------------
constexpr int Bn = 256;    // batch
constexpr int Ln = 200;    // seq len
constexpr int Dn = 128;    // node dim
constexpr int Hn = 128;    // AUGRU hidden
constexpr int C0 = 80;     // attn fc0 width
constexpr int C1 = 40;     // attn fc1 width
constexpr int T0 = 200;    // task fc0 width
constexpr int T1 = 80;     // task fc1 width
constexpr int POOLN = 30;
constexpr float EPS = 1e-4f;
constexpr float NEGINF = -1e30f;
constexpr float NEGBIG = -4294967295.0f;

__device__ __forceinline__ float lrelu(float x) { return x > 0.f ? x : 0.01f * x; }
__device__ __forceinline__ float sigmoidf(float x) { return 1.f / (1.f + expf(-x)); }
// order-preserving float<->int key for atomic min/max
__device__ __forceinline__ int fkey(float f) { int i = __float_as_int(f); return i < 0 ? (i ^ 0x7fffffff) : i; }
__device__ __forceinline__ float funkey(int k) { return __int_as_float(k < 0 ? (k ^ 0x7fffffff) : k); }

// ---------------- build X, tgt, mask ----------------
__global__ void build_x_kernel(const int* his_pro, const int* his_y,
                               const float* item_emb, const float* ans_emb, float* X) {
    int l = blockIdx.x, b = blockIdx.y, t = threadIdx.x; // 128 threads
    size_t row = ((size_t)b * Ln + l) * Dn;
    if (t < 64) X[row + t] = item_emb[(size_t)his_pro[b * Ln + l] * 64 + t];
    else        X[row + t] = ans_emb[his_y[b * Ln + l] * 64 + (t - 64)];
}

__global__ void build_tgt_mask_kernel(const int* cur_pro, const int* his_len,
                                      const float* item_emb, float* tgt, float* mask) {
    int b = blockIdx.x, t = threadIdx.x; // 256 threads
    if (t < 64) tgt[b * Dn + t] = item_emb[(size_t)cur_pro[b] * 64 + t];
    else if (t < 128) tgt[b * Dn + t] = 0.f;
    if (t < Ln) mask[b * Ln + t] = (t < his_len[b]) ? 1.f : 0.f;
}

// ---------------- Xf = normalize(X * w) ----------------
__global__ void xf_kernel(const float* X, const float* wt, float* Xf) {
    int l = blockIdx.x, b = blockIdx.y, t = threadIdx.x; // 128
    __shared__ float red[128];
    size_t row = ((size_t)b * Ln + l) * Dn;
    float v = X[row + t] * wt[t];
    red[t] = v * v;
    __syncthreads();
    for (int s = 64; s > 0; s >>= 1) { if (t < s) red[t] += red[t + s]; __syncthreads(); }
    float norm = fmaxf(sqrtf(red[0]), 1e-12f);
    Xf[row + t] = v / norm;
}

// ---------------- S = Xf Xf^T per batch (raw dots) + per-row min/max ----------------
__global__ __launch_bounds__(256) void s2_gemm_kernel(const float* Xf, float* S,
                                                      float* rowmin, float* rowmax) {
    int b = blockIdx.x, t = threadIdx.x;
    __shared__ float Xl[208 * 132];      // padded rows (200..207 garbage, never stored)
    __shared__ int mnI[200], mxI[200];
    const float4* src = (const float4*)(Xf + (size_t)b * Ln * Dn);
    for (int i = t; i < 6400; i += 256) {
        int row = i >> 5, c4 = i & 31;
        *(float4*)&Xl[row * 132 + c4 * 4] = src[i];
    }
    for (int i = t; i < 200; i += 256) { mnI[i] = 0x7fffffff; mxI[i] = (int)0x80000000; }
    __syncthreads();
    int ty = t >> 4, tx = t & 15;
    float* Sb = S + (size_t)b * Ln * Ln;
    // main region: rows pairs (ri=2rg,2rg+1), cols groups of 4 (ci=4cg..4cg+3)
    for (int rg = 0; rg < 6; ++rg) {
        int l0 = ty + 32 * rg, l1 = l0 + 16;            // both < 192+16 -> <=191, valid
        for (int cg = 0; cg < 3; ++cg) {
            int m0 = tx + 64 * cg;                       // cols m0 + 16j, j<4, all <=191
            float acc[2][4] = {{0,0,0,0},{0,0,0,0}};
            for (int k = 0; k < 128; ++k) {
                float a0 = Xl[l0 * 132 + k], a1 = Xl[l1 * 132 + k];
                float b0 = Xl[(m0) * 132 + k];
                float b1 = Xl[(m0 + 16) * 132 + k];
                float b2 = Xl[(m0 + 32) * 132 + k];
                float b3 = Xl[(m0 + 48) * 132 + k];
                acc[0][0] += a0 * b0; acc[0][1] += a0 * b1; acc[0][2] += a0 * b2; acc[0][3] += a0 * b3;
                acc[1][0] += a1 * b0; acc[1][1] += a1 * b1; acc[1][2] += a1 * b2; acc[1][3] += a1 * b3;
            }
            #pragma unroll
            for (int rr = 0; rr < 2; ++rr) {
                int l = rr ? l1 : l0;
                float mn4 = fminf(fminf(acc[rr][0], acc[rr][1]), fminf(acc[rr][2], acc[rr][3]));
                float mx4 = fmaxf(fmaxf(acc[rr][0], acc[rr][1]), fmaxf(acc[rr][2], acc[rr][3]));
                atomicMin(&mnI[l], fkey(mn4));
                atomicMax(&mxI[l], fkey(mx4));
                #pragma unroll
                for (int j = 0; j < 4; ++j) Sb[l * Ln + m0 + 16 * j] = acc[rr][j];
            }
        }
        // col edge: m = tx + 192 (valid iff tx < 8)
        {
            int m = tx + 192;
            float a0 = 0.f, a1 = 0.f;
            for (int k = 0; k < 128; ++k) {
                float bv = Xl[m * 132 + k];
                a0 += Xl[l0 * 132 + k] * bv;
                a1 += Xl[l1 * 132 + k] * bv;
            }
            if (m < 200) {
                Sb[l0 * Ln + m] = a0;
                Sb[l1 * Ln + m] = a1;
                atomicMin(&mnI[l0], fkey(a0)); atomicMax(&mxI[l0], fkey(a0));
                atomicMin(&mnI[l1], fkey(a1)); atomicMax(&mxI[l1], fkey(a1));
            }
        }
    }
    // row edge: l = ty + 192 (valid iff ty < 8)
    {
        int l = ty + 192;
        for (int cg = 0; cg < 3; ++cg) {
            int m0 = tx + 64 * cg;
            float acc[4] = {0,0,0,0};
            for (int k = 0; k < 128; ++k) {
                float a = Xl[l * 132 + k];
                acc[0] += a * Xl[(m0) * 132 + k];
                acc[1] += a * Xl[(m0 + 16) * 132 + k];
                acc[2] += a * Xl[(m0 + 32) * 132 + k];
                acc[3] += a * Xl[(m0 + 48) * 132 + k];
            }
            if (l < 200) {
                float mn4 = fminf(fminf(acc[0], acc[1]), fminf(acc[2], acc[3]));
                float mx4 = fmaxf(fmaxf(acc[0], acc[1]), fmaxf(acc[2], acc[3]));
                atomicMin(&mnI[l], fkey(mn4));
                atomicMax(&mxI[l], fkey(mx4));
                #pragma unroll
                for (int j = 0; j < 4; ++j) Sb[l * Ln + m0 + 16 * j] = acc[j];
            }
        }
        int m = tx + 192;
        float a0 = 0.f;
        for (int k = 0; k < 128; ++k) a0 += Xl[l * 132 + k] * Xl[m * 132 + k];
        if (l < 200 && m < 200) {
            Sb[l * Ln + m] = a0;
            atomicMin(&mnI[l], fkey(a0)); atomicMax(&mxI[l], fkey(a0));
        }
    }
    __syncthreads();
    for (int i = t; i < 200; i += 256) {
        rowmin[b * Ln + i] = funkey(mnI[i]);
        rowmax[b * Ln + i] = funkey(mxI[i]);
    }
}

// ---------------- in-place scale + mask + edge count ----------------
__global__ __launch_bounds__(256) void s2_scale_kernel(float* S, const float* rowmin,
                                                       const float* rowmax, const float* mask,
                                                       int* nedges) {
    int b = blockIdx.x, t = threadIdx.x;
    __shared__ float mn_s[200], mx_s[200], mk[200];
    __shared__ int red[256];
    for (int i = t; i < 200; i += 256) {
        mn_s[i] = rowmin[b * Ln + i];
        mx_s[i] = rowmax[b * Ln + i];
        mk[i] = mask[b * Ln + i];
    }
    __syncthreads();
    float* Sb = S + (size_t)b * Ln * Ln;
    int cnt = 0;
    for (int idx = t; idx < Ln * Ln; idx += 256) {
        int r = idx / Ln, c = idx % Ln;
        float v = Sb[idx];
        float mn = mn_s[r], d = mx_s[r] - mn;
        float sc = (d > 0.f) ? (v - mn) / d : 0.f;   // nan_to_num(0/0)=0
        sc *= mk[r] * mk[c];
        cnt += (sc != 0.f);
        Sb[idx] = sc;
    }
    red[t] = cnt;
    __syncthreads();
    for (int s = 128; s > 0; s >>= 1) { if (t < s) red[t] += red[t + s]; __syncthreads(); }
    if (t == 0) nedges[b] = red[0];
}

// ---------------- exact k-th largest via radix select ----------------
__global__ void radix_select_kernel(const float* S, const int* nedges, float* thrA) {
    int b = blockIdx.x, t = threadIdx.x; // 256
    __shared__ unsigned int hist[256];
    __shared__ unsigned int prefix;
    __shared__ int kk;
    const unsigned int* data = (const unsigned int*)(S + (size_t)b * Ln * Ln);
    if (t == 0) { prefix = 0u; kk = (nedges[b] + 1) >> 1; } // ceil(n*0.5)
    __syncthreads();
    for (int pass = 0; pass < 4; ++pass) {
        int shift = 24 - 8 * pass;
        hist[t] = 0u;
        __syncthreads();
        unsigned int pmask = (pass == 0) ? 0u : (0xFFFFFFFFu << (shift + 8));
        unsigned int pref = prefix;
        for (int i = t; i < Ln * Ln; i += 256) {
            unsigned int x = data[i];
            if ((x & pmask) == pref) atomicAdd(&hist[(x >> shift) & 255u], 1u);
        }
        __syncthreads();
        if (t == 0) {
            int k = kk;
            for (int bin = 255; bin >= 0; --bin) {
                int c = (int)hist[bin];
                if (k < c) { prefix = pref | ((unsigned int)bin << shift); break; }
                k -= c;
            }
            kk = k;
        }
        __syncthreads();
    }
    if (t == 0) thrA[b] = __uint_as_float(prefix);
}

// ---------------- degree -> dis = rsqrt(deg) ----------------
__global__ void deg_kernel(const float* S, const float* thrA, float* dis) {
    int l = blockIdx.x, b = blockIdx.y, t = threadIdx.x; // 64
    __shared__ float red[64];
    float thr = thrA[b];
    const float* row = S + ((size_t)b * Ln + l) * Ln;
    int cnt = 0;
    for (int m = t; m < Ln; m += 64) if (m != l && row[m] > thr) cnt++;
    red[t] = (float)cnt; __syncthreads();
    for (int s = 32; s > 0; s >>= 1) { if (t < s) red[t] += red[t + s]; __syncthreads(); }
    if (t == 0) dis[b * Ln + l] = rsqrtf(red[0] + 1.f); // +1 self loop
}

// ---------------- An = A_bool * dis_l * dis_m (in-place over S) ----------------
__global__ void an_kernel(float* S, const float* thrA, const float* dis) {
    size_t idx = (size_t)blockIdx.x * 256 + threadIdx.x;
    if (idx >= (size_t)Bn * Ln * Ln) return;
    int b = (int)(idx / (Ln * Ln));
    int rem = (int)(idx % (Ln * Ln));
    int l = rem / Ln, m = rem % Ln;
    float ab = (l == m) ? 1.f : ((S[idx] > thrA[b]) ? 1.f : 0.f);
    S[idx] = ab * dis[b * Ln + l] * dis[b * Ln + m];
}

// ---------------- C = An @ M per batch (M staged in LDS) ----------------
__global__ __launch_bounds__(256) void an_mm2_kernel(const float* An, const float* M, float* C) {
    int b = blockIdx.x, t = threadIdx.x;
    __shared__ float Ml[200 * 128];    // 102.4 KB
    __shared__ float At[16 * 200];     // 12.8 KB
    const float4* src = (const float4*)(M + (size_t)b * Ln * Dn);
    for (int i = t; i < 6400; i += 256) ((float4*)Ml)[i] = src[i];
    int d0 = t & 63, rg = t >> 6;      // rg 0..3, rows rg*4..+3 within tile
    for (int rb = 0; rb < 13; ++rb) {
        int base = rb * 16;
        int nrows = (base + 16 <= Ln) ? 16 : (Ln - base);
        __syncthreads();               // protect At (and Ml on first iter)
        for (int i = t; i < nrows * 200; i += 256)
            At[i] = An[((size_t)b * Ln + base + i / 200) * Ln + (i % 200)];
        __syncthreads();
        if (rg * 4 < nrows) {
            float acc[4][2] = {{0,0},{0,0},{0,0},{0,0}};
            for (int m = 0; m < Ln; ++m) {
                float w0 = Ml[m * 128 + d0];
                float w1 = Ml[m * 128 + d0 + 64];
                #pragma unroll
                for (int ii = 0; ii < 4; ++ii) {
                    float a = At[(rg * 4 + ii) * 200 + m];
                    acc[ii][0] += a * w0;
                    acc[ii][1] += a * w1;
                }
            }
            #pragma unroll
            for (int ii = 0; ii < 4; ++ii) {
                size_t orow = (size_t)b * Ln + base + rg * 4 + ii;
                C[orow * 128 + d0] = acc[ii][0];
                C[orow * 128 + d0 + 64] = acc[ii][1];
            }
        }
    }
}

// ---------------- out = in @ W128 (+ optional residual & leaky relu) ----------------
template<int RES>
__global__ __launch_bounds__(512) void ai2_kernel(const float* in, const float* Wm,
                                                  float* out, const float* res) {
    __shared__ float Wl[128 * 128];    // 64 KB
    __shared__ float Rl[128 * 128];    // 64 KB
    int t = threadIdx.x;
    size_t row0 = (size_t)blockIdx.x * 128;
    const float4* wsrc = (const float4*)Wm;
    for (int i = t; i < 4096; i += 512) ((float4*)Wl)[i] = wsrc[i];
    const float4* rsrc = (const float4*)(in + row0 * 128);
    for (int i = t; i < 4096; i += 512) ((float4*)Rl)[i] = rsrc[i];
    __syncthreads();
    int d0 = t & 63, rg = t >> 6;      // 8 groups of 16 rows
    float acc[16][2];
    #pragma unroll
    for (int rr = 0; rr < 16; ++rr) { acc[rr][0] = 0.f; acc[rr][1] = 0.f; }
    for (int k = 0; k < 128; ++k) {
        float w0 = Wl[k * 128 + d0], w1 = Wl[k * 128 + d0 + 64];
        #pragma unroll
        for (int rr = 0; rr < 16; ++rr) {
            float x = Rl[(rg * 16 + rr) * 128 + k];
            acc[rr][0] += x * w0;
            acc[rr][1] += x * w1;
        }
    }
    #pragma unroll
    for (int rr = 0; rr < 16; ++rr) {
        size_t orow = row0 + rg * 16 + rr;
        float v0 = acc[rr][0], v1 = acc[rr][1];
        if (RES) {
            v0 = lrelu(v0 + res[orow * 128 + d0]);
            v1 = lrelu(v1 + res[orow * 128 + d0 + 64]);
        }
        out[orow * 128 + d0] = v0;
        out[orow * 128 + d0 + 64] = v1;
    }
}

// ---------------- attn fc0: z0 = [ai,q,ai-q,ai*q] @ w0 + b0, fused BN stats ----------------
__global__ __launch_bounds__(256) void fc02_kernel(const float* ai, const float* query, int q3d,
                                                   const float* w0, const float* b0,
                                                   float* z0, float* stats0) {
    __shared__ float F[64 * 129];      // 33 KB feature chunk (padded)
    __shared__ float W[128 * 80];      // 40 KB weight chunk
    __shared__ float sums[160];
    int t = threadIdx.x;
    size_t row0 = (size_t)blockIdx.x * 64;
    float areg[32], qreg[32];
    #pragma unroll
    for (int j = 0; j < 32; ++j) {
        int i = t + j * 256;
        int r = i >> 7, k = i & 127;
        size_t grow = row0 + r;
        areg[j] = ai[grow * 128 + k];
        qreg[j] = q3d ? query[grow * 128 + k] : query[(grow / Ln) * 128 + k];
    }
    int r0 = (t & 31) * 2, cg = t >> 5;  // cols cg*10 + j
    float acc[2][10];
    #pragma unroll
    for (int j = 0; j < 10; ++j) { acc[0][j] = 0.f; acc[1][j] = 0.f; }
    for (int c = 0; c < 4; ++c) {
        if (c) __syncthreads();          // previous chunk's readers done
        #pragma unroll
        for (int j = 0; j < 32; ++j) {
            int i = t + j * 256;
            int r = i >> 7, k = i & 127;
            float a = areg[j], q = qreg[j];
            float f = (c == 0) ? a : (c == 1) ? q : (c == 2) ? (a - q) : (a * q);
            F[r * 129 + k] = f;
        }
        for (int i = t; i < 10240; i += 256) W[i] = w0[c * 10240 + i];
        __syncthreads();
        for (int k = 0; k < 128; ++k) {
            float f0 = F[r0 * 129 + k], f1v = F[(r0 + 1) * 129 + k];
            #pragma unroll
            for (int j = 0; j < 10; ++j) {
                float w = W[k * 80 + cg * 10 + j];
                acc[0][j] += f0 * w;
                acc[1][j] += f1v * w;
            }
        }
    }
    __syncthreads();
    if (t < 160) sums[t] = 0.f;
    __syncthreads();
    #pragma unroll
    for (int j = 0; j < 10; ++j) {
        float bb = b0[cg * 10 + j];
        float z0v = acc[0][j] + bb;
        float z1v = acc[1][j] + bb;
        z0[(row0 + r0) * 80 + cg * 10 + j] = z0v;
        z0[(row0 + r0 + 1) * 80 + cg * 10 + j] = z1v;
        atomicAdd(&sums[cg * 10 + j], z0v + z1v);
        atomicAdd(&sums[80 + cg * 10 + j], z0v * z0v + z1v * z1v);
    }
    __syncthreads();
    if (t < 80) {
        atomicAdd(&stats0[t], sums[t]);
        atomicAdd(&stats0[80 + t], sums[80 + t]);
    }
}

// ---------------- attn fc1: BN(z0)->relu -> @w1 + b1, fused BN stats ----------------
__global__ __launch_bounds__(256) void fc1b_kernel(const float* z0, const float* stats0,
                                                   const float* g0, const float* be0,
                                                   const float* w1, const float* b1,
                                                   float* z1, float* stats1, int N) {
    __shared__ float Y[64 * 81];
    __shared__ float W1s[80 * 40];
    __shared__ float mnA[80], rsA[80], gA[80], beA[80];
    __shared__ float sums[80];
    int t = threadIdx.x;
    size_t row0 = (size_t)blockIdx.x * 64;
    if (t < 80) {
        float mean = stats0[t] / N;
        float var = stats0[80 + t] / N - mean * mean;
        mnA[t] = mean; rsA[t] = rsqrtf(var + EPS); gA[t] = g0[t]; beA[t] = be0[t];
    }
    for (int i = t; i < 3200; i += 256) W1s[i] = w1[i];
    __syncthreads();
    for (int i = t; i < 5120; i += 256) {
        int r = i / 80, k = i % 80;
        float v = z0[row0 * 80 + i];
        float y = (v - mnA[k]) * rsA[k] * gA[k] + beA[k];
        Y[r * 81 + k] = fmaxf(y, 0.f);
    }
    __syncthreads();
    int r0 = (t & 31) * 2, cg = t >> 5;  // cols cg*5 + j
    float acc[2][5];
    #pragma unroll
    for (int j = 0; j < 5; ++j) { acc[0][j] = 0.f; acc[1][j] = 0.f; }
    for (int k = 0; k < 80; ++k) {
        float y0 = Y[r0 * 81 + k], y1 = Y[(r0 + 1) * 81 + k];
        #pragma unroll
        for (int j = 0; j < 5; ++j) {
            float w = W1s[k * 40 + cg * 5 + j];
            acc[0][j] += y0 * w;
            acc[1][j] += y1 * w;
        }
    }
    __syncthreads();
    if (t < 80) sums[t] = 0.f;
    __syncthreads();
    #pragma unroll
    for (int j = 0; j < 5; ++j) {
        float bb = b1[cg * 5 + j];
        float z0v = acc[0][j] + bb;
        float z1v = acc[1][j] + bb;
        z1[(row0 + r0) * 40 + cg * 5 + j] = z0v;
        z1[(row0 + r0 + 1) * 40 + cg * 5 + j] = z1v;
        atomicAdd(&sums[cg * 5 + j], z0v + z1v);
        atomicAdd(&sums[40 + cg * 5 + j], z0v * z0v + z1v * z1v);
    }
    __syncthreads();
    if (t < 40) {
        atomicAdd(&stats1[t], sums[t]);
        atomicAdd(&stats1[40 + t], sums[40 + t]);
    }
}

// ---------------- attn out: o = relu(BN(z1)) @ wo + bo ----------------
__global__ __launch_bounds__(256) void out2_kernel(const float* z1, const float* stats1,
                                                   const float* g1, const float* be1,
                                                   const float* wo, const float* bo,
                                                   float* o, int N) {
    __shared__ float Zs[256 * 41];
    __shared__ float mnA[40], rsA[40], gA[40], beA[40], woA[40];
    int t = threadIdx.x;
    size_t row0 = (size_t)blockIdx.x * 256;
    if (t < 40) {
        float mean = stats1[t] / N;
        float var = stats1[40 + t] / N - mean * mean;
        mnA[t] = mean; rsA[t] = rsqrtf(var + EPS);
        gA[t] = g1[t]; beA[t] = be1[t]; woA[t] = wo[t];
    }
    __syncthreads();
    for (int i = t; i < 10240; i += 256) {
        int r = i / 40, k = i % 40;
        float v = z1[row0 * 40 + i];
        float y = (v - mnA[k]) * rsA[k] * gA[k] + beA[k];
        Zs[r * 41 + k] = fmaxf(y, 0.f);
    }
    __syncthreads();
    float acc = bo[0];
    for (int k = 0; k < 40; ++k) acc += Zs[t * 41 + k] * woA[k];
    o[row0 + t] = acc;
}

// softmax over L with mask; optional second addend; optional *mask on output
__global__ void masked_softmax_kernel(const float* o, const float* o2, const float* mask,
                                      float neg, int mulmask, float* w) {
    int b = blockIdx.x, t = threadIdx.x; // 256
    __shared__ float buf[Ln];
    __shared__ float red[256];
    if (t < Ln) {
        float x = o[b * Ln + t];
        if (o2) x += o2[b * Ln + t];
        buf[t] = (mask[b * Ln + t] > 0.f) ? x : neg;
    }
    __syncthreads();
    red[t] = (t < Ln) ? buf[t] : -3.4e38f;
    __syncthreads();
    for (int s = 128; s > 0; s >>= 1) { if (t < s) red[t] = fmaxf(red[t], red[t + s]); __syncthreads(); }
    float mx = red[0];
    __syncthreads();
    float e = 0.f;
    if (t < Ln) e = expf(buf[t] - mx);
    red[t] = e;
    __syncthreads();
    for (int s = 128; s > 0; s >>= 1) { if (t < s) red[t] += red[t + s]; __syncthreads(); }
    float sm = red[0];
    if (t < Ln) {
        float v = e / sm;
        if (mulmask) v *= mask[b * Ln + t];
        w[b * Ln + t] = v;
    }
}

// ---------------- E row-softmax + ex = P @ X (per batch) ----------------
__global__ __launch_bounds__(256) void fxc_p_kernel(const float* An, const float* f1, const float* f2,
                                                    const float* X, float* ex) {
    __shared__ float Xl[200 * 128];    // 102.4 KB
    __shared__ float p[4][200];
    __shared__ float invs[4];
    __shared__ float f1s[200];
    int b = blockIdx.x, t = threadIdx.x;
    const float4* src = (const float4*)(X + (size_t)b * Ln * Dn);
    for (int i = t; i < 6400; i += 256) ((float4*)Xl)[i] = src[i];
    for (int i = t; i < 200; i += 256) f1s[i] = f1[b * Ln + i];
    __syncthreads();
    int wv = t >> 6, lane = t & 63;
    for (int l0 = 0; l0 < Ln; l0 += 4) {
        int l = l0 + wv;
        float f2l = f2[b * Ln + l];
        const float* Arow = An + ((size_t)b * Ln + l) * Ln;
        float e[4]; float mx = -3.4e38f;
        #pragma unroll
        for (int j = 0; j < 4; ++j) {
            int m = lane + 64 * j;
            float ev = NEGINF;
            if (m < Ln) {
                float ab = Arow[m];
                if (ab > 0.f) { float s = f1s[m] + f2l; ev = (s > 0.f) ? s : 0.01f * s; }
            }
            e[j] = ev; mx = fmaxf(mx, ev);
        }
        for (int off = 32; off > 0; off >>= 1) mx = fmaxf(mx, __shfl_xor(mx, off));
        float sm = 0.f;
        #pragma unroll
        for (int j = 0; j < 4; ++j) {
            int m = lane + 64 * j;
            float pe = (m < Ln) ? expf(e[j] - mx) : 0.f;
            if (m < Ln) p[wv][m] = pe;
            sm += pe;
        }
        for (int off = 32; off > 0; off >>= 1) sm += __shfl_xor(sm, off);
        if (lane == 0) invs[wv] = 1.f / sm;
        __syncthreads();
        int d0 = lane * 2;
        float a0 = 0.f, a1 = 0.f;
        const float* pr = p[wv];
        for (int m = 0; m < Ln; ++m) {
            float pm = pr[m];
            float2 x2 = *(const float2*)&Xl[m * 128 + d0];
            a0 += pm * x2.x;
            a1 += pm * x2.y;
        }
        float inv = invs[wv];
        size_t orow = (size_t)b * Ln + l;
        ex[orow * 128 + d0] = a0 * inv;
        ex[orow * 128 + d0 + 1] = a1 * inv;
        __syncthreads();
    }
}

// ---------------- pooling: mask2 = cs > (k-th largest), order, red_len ----------------
__global__ void pool_kernel(const float* cs, const int* his_len, float* mask2,
                            int* order, int* red_len) {
    int b = blockIdx.x, t = threadIdx.x; // 256
    __shared__ float v[Ln];
    __shared__ float thr;
    if (t < Ln) v[t] = cs[b * Ln + t];
    __syncthreads();
    int k = min(his_len[b], POOLN);
    if (t < Ln) {
        float x = v[t];
        int gt = 0, eq = 0;
        for (int i = 0; i < Ln; ++i) { gt += (v[i] > x); eq += (v[i] == x); }
        if (gt <= k && k < gt + eq) thr = x; // the k-th order statistic (desc)
    }
    __syncthreads();
    if (t < Ln) mask2[b * Ln + t] = (v[t] > thr) ? 1.f : 0.f;
    __syncthreads();
    if (t == 0) {
        int idx = 0;
        for (int l = 0; l < Ln; ++l) if (v[l] > thr) order[b * Ln + idx++] = l;
        red_len[b] = idx;
        for (int l = 0; l < Ln; ++l) if (!(v[l] > thr)) order[b * Ln + idx++] = l;
    }
}

__global__ void readout_kernel(const float* Xc, const float* cs, const float* mask2, float* gr) {
    int b = blockIdx.x, t = threadIdx.x; // 128
    float acc = 0.f;
    for (int l = 0; l < Ln; ++l)
        acc += Xc[((size_t)b * Ln + l) * Dn + t] * cs[b * Ln + l] * mask2[b * Ln + l];
    gr[b * Dn + t] = acc;
}

__global__ void gather_kernel(const float* Xc, const float* mask2, const int* order,
                              float* Xs, float* mask_s) {
    int i = blockIdx.x, b = blockIdx.y, t = threadIdx.x; // 128
    int src = order[b * Ln + i];
    Xs[((size_t)b * Ln + i) * Dn + t] = Xc[((size_t)b * Ln + src) * Dn + t];
    if (t == 0) mask_s[b * Ln + i] = mask2[b * Ln + src];
}

// ---------------- AUGRU ----------------
__global__ void xp_kernel(const float* Xs, const float* Wx, const float* bx, float* xp) {
    int l = blockIdx.x, b = blockIdx.y, t = threadIdx.x; // 384
    __shared__ float x[Dn];
    if (t < Dn) x[t] = Xs[((size_t)b * Ln + l) * Dn + t];
    __syncthreads();
    float acc = bx[t];
    for (int d = 0; d < Dn; ++d) acc += x[d] * Wx[d * 384 + t];
    xp[((size_t)b * POOLN + l) * 384 + t] = acc;
}

__global__ void augru_kernel(const float* xp, const float* alphas, const int* red_len,
                             const float* Wh, const float* bh, float* final_h) {
    int b = blockIdx.x, j = threadIdx.x; // 128
    __shared__ float h[Hn];
    h[j] = 0.f;
    __syncthreads();
    int T = red_len[b];
    for (int step = 0; step < T; ++step) {
        float hr = bh[j], hu = bh[Hn + j], hn = bh[2 * Hn + j];
        for (int k = 0; k < Hn; ++k) {
            float hk = h[k];
            hr += hk * Wh[k * 384 + j];
            hu += hk * Wh[k * 384 + Hn + j];
            hn += hk * Wh[k * 384 + 2 * Hn + j];
        }
        const float* xrow = xp + ((size_t)b * POOLN + step) * 384;
        float a = alphas[b * Ln + step];
        float r = sigmoidf(xrow[j] + hr);
        float u = sigmoidf(xrow[Hn + j] + hu) * a;
        float n = tanhf(xrow[2 * Hn + j] + r * hn);
        float hnew = (1.f - u) * h[j] + u * n;
        __syncthreads();
        h[j] = hnew;
        __syncthreads();
    }
    final_h[b * Hn + j] = h[j];
}

// ---------------- head ----------------
__global__ void mo_kernel(const float* final_h, const float* gr, const float* tgt, float* mo) {
    int b = blockIdx.x, t = threadIdx.x; // 128
    mo[b * 512 + t] = final_h[b * Hn + t];
    mo[b * 512 + 128 + t] = gr[b * Dn + t];
    mo[b * 512 + 256 + t] = tgt[b * Dn + t];
    mo[b * 512 + 384 + t] = gr[b * Dn + t] * tgt[b * Dn + t];
}

// stats[c] = sum, stats[C+c] = sumsq.  blockDim=(C,TY)
__global__ void bn_stats_kernel(const float* z, int N, int C, float* stats) {
    int c = threadIdx.x;
    extern __shared__ float red[]; // 2*C*TY
    float s = 0.f, q = 0.f;
    for (int r = blockIdx.x * blockDim.y + threadIdx.y; r < N; r += gridDim.x * blockDim.y) {
        float v = z[(size_t)r * C + c];
        s += v; q += v * v;
    }
    red[threadIdx.y * C + c] = s;
    red[blockDim.y * C + threadIdx.y * C + c] = q;
    __syncthreads();
    if (threadIdx.y == 0) {
        for (int ty = 1; ty < (int)blockDim.y; ++ty) {
            s += red[ty * C + c];
            q += red[blockDim.y * C + ty * C + c];
        }
        atomicAdd(&stats[c], s);
        atomicAdd(&stats[C + c], q);
    }
}

// generic dense layer: optional BN+relu on input, then y = in' @ w + bias
__global__ void head_fc_kernel(const float* in, int K, int C, const float* w, const float* bias,
                               const float* stats, int statN, const float* g, const float* be,
                               float* out) {
    int b = blockIdx.x;
    extern __shared__ float y[]; // K floats
    for (int k = threadIdx.x; k < K; k += blockDim.x) {
        float v = in[(size_t)b * K + k];
        if (stats) {
            float mean = stats[k] / statN;
            float var = stats[K + k] / statN - mean * mean;
            v = fmaxf((v - mean) * rsqrtf(var + EPS) * g[k] + be[k], 0.f);
        }
        y[k] = v;
    }
    __syncthreads();
    for (int c = threadIdx.x; c < C; c += blockDim.x) {
        float acc = bias[c];
        for (int k = 0; k < K; ++k) acc += y[k] * w[k * C + c];
        out[(size_t)b * C + c] = acc;
    }
}

// ---------------- host driver ----------------
struct AttnParams {
    const float *w0, *b0, *g0, *be0, *w1, *b1, *g1, *be1, *wo, *bo;
};

static void run_attn_fcn(hipStream_t stream, const float* kv, const float* query, int q3d,
                         const float* mat, const float* mask, const AttnParams& P,
                         float* ai, float* z0, float* z1, float* o,
                         float* stats0, float* stats1, float* out_w) {
    ai2_kernel<0><<<400, 512, 0, stream>>>(kv, mat, ai, nullptr);
    hipMemsetAsync(stats0, 0, 160 * sizeof(float), stream);
    fc02_kernel<<<800, 256, 0, stream>>>(ai, query, q3d, P.w0, P.b0, z0, stats0);
    hipMemsetAsync(stats1, 0, 80 * sizeof(float), stream);
    fc1b_kernel<<<800, 256, 0, stream>>>(z0, stats0, P.g0, P.be0, P.w1, P.b1, z1, stats1, Bn * Ln);
    out2_kernel<<<200, 256, 0, stream>>>(z1, stats1, P.g1, P.be1, P.wo, P.bo, o, Bn * Ln);
    masked_softmax_kernel<<<Bn, 256, 0, stream>>>(o, nullptr, mask, NEGINF, 0, out_w);
}

extern "C" void kernel_launch(void* const* d_in, const int* in_sizes, int n_in,
                              void* d_out, int out_size, void* d_ws, size_t ws_size,
                              hipStream_t stream) {
    (void)in_sizes; (void)n_in; (void)out_size; (void)ws_size;
    const int* his_pro = (const int*)d_in[0];
    const int* his_y   = (const int*)d_in[1];
    const int* his_len = (const int*)d_in[2];
    const int* cur_pro = (const int*)d_in[3];
    const float* item_emb    = (const float*)d_in[5];
    const float* ans_emb     = (const float*)d_in[6];
    const float* wt          = (const float*)d_in[7];
    const float* att_cluster = (const float*)d_in[8];
    const float* att_query   = (const float*)d_in[9];
    const float* att_rnn     = (const float*)d_in[10];
    const float* aggre_W     = (const float*)d_in[11];
    const float* gru_Wx = (const float*)d_in[12];
    const float* gru_Wh = (const float*)d_in[13];
    const float* gru_bx = (const float*)d_in[14];
    const float* gru_bh = (const float*)d_in[15];
    AttnParams AP;
    AP.w0 = (const float*)d_in[16]; AP.b0 = (const float*)d_in[17];
    AP.g0 = (const float*)d_in[18]; AP.be0 = (const float*)d_in[19];
    AP.w1 = (const float*)d_in[20]; AP.b1 = (const float*)d_in[21];
    AP.g1 = (const float*)d_in[22]; AP.be1 = (const float*)d_in[23];
    AP.wo = (const float*)d_in[24]; AP.bo = (const float*)d_in[25];
    const float* t_w0 = (const float*)d_in[26];
    const float* t_b0 = (const float*)d_in[27];
    const float* t_g0 = (const float*)d_in[28];
    const float* t_be0 = (const float*)d_in[29];
    const float* t_w1 = (const float*)d_in[30];
    const float* t_b1 = (const float*)d_in[31];
    const float* t_g1 = (const float*)d_in[32];
    const float* t_be1 = (const float*)d_in[33];
    const float* t_wo = (const float*)d_in[34];
    const float* t_bo = (const float*)d_in[35];

    // -------- workspace carve --------
    char* p = (char*)d_ws;
    auto alloc = [&](size_t bytes) -> void* {
        void* r = (void*)p;
        p += ((bytes + 255) / 256) * 256;
        return r;
    };
    const size_t NX = (size_t)Bn * Ln * Dn;
    const size_t NS = (size_t)Bn * Ln * Ln;
    float* X    = (float*)alloc(NX * 4);
    float* XfXc = (float*)alloc(NX * 4);   // Xf, later reused as Xc
    float* S    = (float*)alloc(NS * 4);   // S raw -> scaled -> An in-place
    float* tmp  = (float*)alloc(NX * 4);   // An@M temp / attn 'ai' / ex
    float* XqXs = (float*)alloc(NX * 4);   // Xq, later Xs
    float* z0   = (float*)alloc((size_t)Bn * Ln * C0 * 4);
    float* z1   = (float*)alloc((size_t)Bn * Ln * C1 * 4);
    float* obuf = (float*)alloc((size_t)Bn * Ln * 4);
    float* f1   = (float*)alloc((size_t)Bn * Ln * 4);
    float* f2   = (float*)alloc((size_t)Bn * Ln * 4);
    float* alph = (float*)alloc((size_t)Bn * Ln * 4);
    float* mask = (float*)alloc((size_t)Bn * Ln * 4);
    float* tgt  = (float*)alloc((size_t)Bn * Dn * 4);
    float* dis  = (float*)alloc((size_t)Bn * Ln * 4);
    float* thrA = (float*)alloc((size_t)Bn * 4);
    int*   nedges = (int*)alloc((size_t)Bn * 4);
    float* rowmin = (float*)alloc((size_t)Bn * Ln * 4);
    float* rowmax = (float*)alloc((size_t)Bn * Ln * 4);
    float* statsA = (float*)alloc(2 * 200 * 4);
    float* statsB = (float*)alloc(2 * 200 * 4);
    float* cs     = (float*)alloc((size_t)Bn * Ln * 4);
    float* mask2  = (float*)alloc((size_t)Bn * Ln * 4);
    int*   order  = (int*)alloc((size_t)Bn * Ln * 4);
    int*   redlen = (int*)alloc((size_t)Bn * 4);
    float* mask_s = (float*)alloc((size_t)Bn * Ln * 4);
    float* xp     = (float*)alloc((size_t)Bn * POOLN * 384 * 4);
    float* finalh = (float*)alloc((size_t)Bn * Hn * 4);
    float* gr     = (float*)alloc((size_t)Bn * Dn * 4);
    float* mo     = (float*)alloc((size_t)Bn * 512 * 4);
    float* t0buf  = (float*)alloc((size_t)Bn * T0 * 4);
    float* t1buf  = (float*)alloc((size_t)Bn * T1 * 4);

    dim3 gLB(Ln, Bn);

    // ---- inputs ----
    build_x_kernel<<<gLB, 128, 0, stream>>>(his_pro, his_y, item_emb, ans_emb, X);
    build_tgt_mask_kernel<<<Bn, 256, 0, stream>>>(cur_pro, his_len, item_emb, tgt, mask);

    // ---- similarity graph ----
    xf_kernel<<<gLB, 128, 0, stream>>>(X, wt, XfXc);
    s2_gemm_kernel<<<Bn, 256, 0, stream>>>(XfXc, S, rowmin, rowmax);
    s2_scale_kernel<<<Bn, 256, 0, stream>>>(S, rowmin, rowmax, mask, nedges);
    radix_select_kernel<<<Bn, 256, 0, stream>>>(S, nedges, thrA);
    deg_kernel<<<gLB, 64, 0, stream>>>(S, thrA, dis);
    an_kernel<<<(int)((NS + 255) / 256), 256, 0, stream>>>(S, thrA, dis); // S -> An

    // ---- fusion round 1 ----
    an_mm2_kernel<<<Bn, 256, 0, stream>>>(S, X, tmp);
    an_mm2_kernel<<<Bn, 256, 0, stream>>>(S, tmp, XqXs); // Xq
    run_attn_fcn(stream, X, XqXs, 1, att_cluster, mask, AP, tmp, z0, z1, obuf, statsA, statsB, f1);
    run_attn_fcn(stream, X, tgt, 0, att_query, mask, AP, tmp, z0, z1, obuf, statsA, statsB, f2);
    fxc_p_kernel<<<Bn, 256, 0, stream>>>(S, f1, f2, X, tmp);       // ex -> tmp
    ai2_kernel<1><<<400, 512, 0, stream>>>(tmp, aggre_W, XfXc, X); // Xc = lrelu(ex@W + X)

    // ---- fusion round 2 (extraction) ----
    an_mm2_kernel<<<Bn, 256, 0, stream>>>(S, XfXc, tmp);
    an_mm2_kernel<<<Bn, 256, 0, stream>>>(S, tmp, XqXs); // Xq2
    run_attn_fcn(stream, XfXc, XqXs, 1, att_cluster, mask, AP, tmp, z0, z1, obuf, statsA, statsB, f1);
    run_attn_fcn(stream, XfXc, tgt, 0, att_query, mask, AP, tmp, z0, z1, obuf, statsA, statsB, f2);
    masked_softmax_kernel<<<Bn, 256, 0, stream>>>(f1, f2, mask, NEGBIG, 1, cs);

    // ---- pooling ----
    pool_kernel<<<Bn, 256, 0, stream>>>(cs, his_len, mask2, order, redlen);
    readout_kernel<<<Bn, 128, 0, stream>>>(XfXc, cs, mask2, gr);
    gather_kernel<<<gLB, 128, 0, stream>>>(XfXc, mask2, order, XqXs, mask_s); // Xs

    // ---- AUGRU ----
    run_attn_fcn(stream, XqXs, tgt, 0, att_rnn, mask_s, AP, tmp, z0, z1, obuf, statsA, statsB, alph);
    xp_kernel<<<dim3(POOLN, Bn), 384, 0, stream>>>(XqXs, gru_Wx, gru_bx, xp);
    augru_kernel<<<Bn, 128, 0, stream>>>(xp, alph, redlen, gru_Wh, gru_bh, finalh);

    // ---- head ----
    mo_kernel<<<Bn, 128, 0, stream>>>(finalh, gr, tgt, mo);
    head_fc_kernel<<<Bn, 256, 512 * 4, stream>>>(mo, 512, T0, t_w0, t_b0,
                                                 nullptr, 0, nullptr, nullptr, t0buf);
    hipMemsetAsync(statsA, 0, 2 * T0 * sizeof(float), stream);
    bn_stats_kernel<<<32, dim3(T0, 1), 2 * T0 * sizeof(float), stream>>>(t0buf, Bn, T0, statsA);
    head_fc_kernel<<<Bn, 256, T0 * 4, stream>>>(t0buf, T0, T1, t_w1, t_b1,
                                                statsA, Bn, t_g0, t_be0, t1buf);
    hipMemsetAsync(statsB, 0, 2 * T1 * sizeof(float), stream);
    bn_stats_kernel<<<16, dim3(T1, 3), 2 * T1 * 3 * sizeof(float), stream>>>(t1buf, Bn, T1, statsB);
    head_fc_kernel<<<Bn, 256, T1 * 4, stream>>>(t1buf, T1, 1, t_wo, t_bo,
                                                statsB, Bn, t_g1, t_be1, (float*)d_out);
}

// Round 9
// 2734.967 us; speedup vs baseline: 1.9585x; 1.0541x over previous
//
#include <hip/hip_runtime.h>
#include <math.h>

// ---------------- constants ----------------
constexpr int Bn = 256;    // batch
constexpr int Ln = 200;    // seq len
constexpr int Dn = 128;    // node dim
constexpr int Hn = 128;    // AUGRU hidden
constexpr int C0 = 80;     // attn fc0 width
constexpr int C1 = 40;     // attn fc1 width
constexpr int T0 = 200;    // task fc0 width
constexpr int T1 = 80;     // task fc1 width
constexpr int POOLN = 30;
constexpr float EPS = 1e-4f;
constexpr float NEGINF = -1e30f;
constexpr float NEGBIG = -4294967295.0f;

__device__ __forceinline__ float lrelu(float x) { return x > 0.f ? x : 0.01f * x; }
__device__ __forceinline__ float sigmoidf(float x) { return 1.f / (1.f + expf(-x)); }
// order-preserving float<->int key for atomic min/max
__device__ __forceinline__ int fkey(float f) { int i = __float_as_int(f); return i < 0 ? (i ^ 0x7fffffff) : i; }
__device__ __forceinline__ float funkey(int k) { return __int_as_float(k < 0 ? (k ^ 0x7fffffff) : k); }

// ---------------- build X, tgt, mask ----------------
__global__ void build_x_kernel(const int* his_pro, const int* his_y,
                               const float* item_emb, const float* ans_emb, float* X) {
    int l = blockIdx.x, b = blockIdx.y, t = threadIdx.x; // 128 threads
    size_t row = ((size_t)b * Ln + l) * Dn;
    if (t < 64) X[row + t] = item_emb[(size_t)his_pro[b * Ln + l] * 64 + t];
    else        X[row + t] = ans_emb[his_y[b * Ln + l] * 64 + (t - 64)];
}

__global__ void build_tgt_mask_kernel(const int* cur_pro, const int* his_len,
                                      const float* item_emb, float* tgt, float* mask) {
    int b = blockIdx.x, t = threadIdx.x; // 256 threads
    if (t < 64) tgt[b * Dn + t] = item_emb[(size_t)cur_pro[b] * 64 + t];
    else if (t < 128) tgt[b * Dn + t] = 0.f;
    if (t < Ln) mask[b * Ln + t] = (t < his_len[b]) ? 1.f : 0.f;
}

// ---------------- Xf = normalize(X * w) ----------------
__global__ void xf_kernel(const float* X, const float* wt, float* Xf) {
    int l = blockIdx.x, b = blockIdx.y, t = threadIdx.x; // 128
    __shared__ float red[128];
    size_t row = ((size_t)b * Ln + l) * Dn;
    float v = X[row + t] * wt[t];
    red[t] = v * v;
    __syncthreads();
    for (int s = 64; s > 0; s >>= 1) { if (t < s) red[t] += red[t + s]; __syncthreads(); }
    float norm = fmaxf(sqrtf(red[0]), 1e-12f);
    Xf[row + t] = v / norm;
}

// ---------------- S = Xf Xf^T per batch (raw dots) + per-row min/max ----------------
__global__ __launch_bounds__(256) void s2_gemm_kernel(const float* Xf, float* S,
                                                      float* rowmin, float* rowmax) {
    int b = blockIdx.x, t = threadIdx.x;
    __shared__ float Xl[208 * 132];      // padded rows (200..207 garbage, never stored)
    __shared__ int mnI[200], mxI[200];
    const float4* src = (const float4*)(Xf + (size_t)b * Ln * Dn);
    for (int i = t; i < 6400; i += 256) {
        int row = i >> 5, c4 = i & 31;
        *(float4*)&Xl[row * 132 + c4 * 4] = src[i];
    }
    for (int i = t; i < 200; i += 256) { mnI[i] = 0x7fffffff; mxI[i] = (int)0x80000000; }
    __syncthreads();
    int ty = t >> 4, tx = t & 15;
    float* Sb = S + (size_t)b * Ln * Ln;
    // main region: rows pairs (ri=2rg,2rg+1), cols groups of 4 (ci=4cg..4cg+3)
    for (int rg = 0; rg < 6; ++rg) {
        int l0 = ty + 32 * rg, l1 = l0 + 16;            // both < 192+16 -> <=191, valid
        for (int cg = 0; cg < 3; ++cg) {
            int m0 = tx + 64 * cg;                       // cols m0 + 16j, j<4, all <=191
            float acc[2][4] = {{0,0,0,0},{0,0,0,0}};
            for (int k = 0; k < 128; ++k) {
                float a0 = Xl[l0 * 132 + k], a1 = Xl[l1 * 132 + k];
                float b0 = Xl[(m0) * 132 + k];
                float b1 = Xl[(m0 + 16) * 132 + k];
                float b2 = Xl[(m0 + 32) * 132 + k];
                float b3 = Xl[(m0 + 48) * 132 + k];
                acc[0][0] += a0 * b0; acc[0][1] += a0 * b1; acc[0][2] += a0 * b2; acc[0][3] += a0 * b3;
                acc[1][0] += a1 * b0; acc[1][1] += a1 * b1; acc[1][2] += a1 * b2; acc[1][3] += a1 * b3;
            }
            #pragma unroll
            for (int rr = 0; rr < 2; ++rr) {
                int l = rr ? l1 : l0;
                float mn4 = fminf(fminf(acc[rr][0], acc[rr][1]), fminf(acc[rr][2], acc[rr][3]));
                float mx4 = fmaxf(fmaxf(acc[rr][0], acc[rr][1]), fmaxf(acc[rr][2], acc[rr][3]));
                atomicMin(&mnI[l], fkey(mn4));
                atomicMax(&mxI[l], fkey(mx4));
                #pragma unroll
                for (int j = 0; j < 4; ++j) Sb[l * Ln + m0 + 16 * j] = acc[rr][j];
            }
        }
        // col edge: m = tx + 192 (valid iff tx < 8)
        {
            int m = tx + 192;
            float a0 = 0.f, a1 = 0.f;
            for (int k = 0; k < 128; ++k) {
                float bv = Xl[m * 132 + k];
                a0 += Xl[l0 * 132 + k] * bv;
                a1 += Xl[l1 * 132 + k] * bv;
            }
            if (m < 200) {
                Sb[l0 * Ln + m] = a0;
                Sb[l1 * Ln + m] = a1;
                atomicMin(&mnI[l0], fkey(a0)); atomicMax(&mxI[l0], fkey(a0));
                atomicMin(&mnI[l1], fkey(a1)); atomicMax(&mxI[l1], fkey(a1));
            }
        }
    }
    // row edge: l = ty + 192 (valid iff ty < 8)
    {
        int l = ty + 192;
        for (int cg = 0; cg < 3; ++cg) {
            int m0 = tx + 64 * cg;
            float acc[4] = {0,0,0,0};
            for (int k = 0; k < 128; ++k) {
                float a = Xl[l * 132 + k];
                acc[0] += a * Xl[(m0) * 132 + k];
                acc[1] += a * Xl[(m0 + 16) * 132 + k];
                acc[2] += a * Xl[(m0 + 32) * 132 + k];
                acc[3] += a * Xl[(m0 + 48) * 132 + k];
            }
            if (l < 200) {
                float mn4 = fminf(fminf(acc[0], acc[1]), fminf(acc[2], acc[3]));
                float mx4 = fmaxf(fmaxf(acc[0], acc[1]), fmaxf(acc[2], acc[3]));
                atomicMin(&mnI[l], fkey(mn4));
                atomicMax(&mxI[l], fkey(mx4));
                #pragma unroll
                for (int j = 0; j < 4; ++j) Sb[l * Ln + m0 + 16 * j] = acc[j];
            }
        }
        int m = tx + 192;
        float a0 = 0.f;
        for (int k = 0; k < 128; ++k) a0 += Xl[l * 132 + k] * Xl[m * 132 + k];
        if (l < 200 && m < 200) {
            Sb[l * Ln + m] = a0;
            atomicMin(&mnI[l], fkey(a0)); atomicMax(&mxI[l], fkey(a0));
        }
    }
    __syncthreads();
    for (int i = t; i < 200; i += 256) {
        rowmin[b * Ln + i] = funkey(mnI[i]);
        rowmax[b * Ln + i] = funkey(mxI[i]);
    }
}

// ---------------- in-place scale + mask + edge count ----------------
__global__ __launch_bounds__(256) void s2_scale_kernel(float* S, const float* rowmin,
                                                       const float* rowmax, const float* mask,
                                                       int* nedges) {
    int b = blockIdx.x, t = threadIdx.x;
    __shared__ float mn_s[200], mx_s[200], mk[200];
    __shared__ int red[256];
    for (int i = t; i < 200; i += 256) {
        mn_s[i] = rowmin[b * Ln + i];
        mx_s[i] = rowmax[b * Ln + i];
        mk[i] = mask[b * Ln + i];
    }
    __syncthreads();
    float* Sb = S + (size_t)b * Ln * Ln;
    int cnt = 0;
    for (int idx = t; idx < Ln * Ln; idx += 256) {
        int r = idx / Ln, c = idx % Ln;
        float v = Sb[idx];
        float mn = mn_s[r], d = mx_s[r] - mn;
        float sc = (d > 0.f) ? (v - mn) / d : 0.f;   // nan_to_num(0/0)=0
        sc *= mk[r] * mk[c];
        cnt += (sc != 0.f);
        Sb[idx] = sc;
    }
    red[t] = cnt;
    __syncthreads();
    for (int s = 128; s > 0; s >>= 1) { if (t < s) red[t] += red[t + s]; __syncthreads(); }
    if (t == 0) nedges[b] = red[0];
}

// ---------------- exact k-th largest via radix select (v2) ----------------
// 1024 threads, per-wave privatized histograms, parallel suffix scan.
__global__ __launch_bounds__(1024) void radix_select2_kernel(const float* S, const int* nedges,
                                                             float* thrA) {
    int b = blockIdx.x, t = threadIdx.x;
    int wv = t >> 6;                      // 16 waves
    __shared__ unsigned int hist[16][256]; // 16 KB
    __shared__ unsigned int comb[256];
    __shared__ unsigned int prefix_s;
    __shared__ int kk;
    const unsigned int* data = (const unsigned int*)(S + (size_t)b * Ln * Ln);
    if (t == 0) { prefix_s = 0u; kk = (nedges[b] + 1) >> 1; } // ceil(n*0.5)
    for (int pass = 0; pass < 4; ++pass) {
        int shift = 24 - 8 * pass;
        for (int i = t; i < 16 * 256; i += 1024) ((unsigned int*)hist)[i] = 0u;
        __syncthreads();                 // hist zeroed; prefix_s/kk visible
        unsigned int pmask = (pass == 0) ? 0u : (0xFFFFFFFFu << (shift + 8));
        unsigned int pref = prefix_s;
        for (int i = t; i < Ln * Ln; i += 1024) {
            unsigned int x = data[i];
            if ((x & pmask) == pref) atomicAdd(&hist[wv][(x >> shift) & 255u], 1u);
        }
        __syncthreads();
        if (t < 256) {
            unsigned int s = 0;
            #pragma unroll
            for (int w = 0; w < 16; ++w) s += hist[w][t];
            comb[t] = s;
        }
        __syncthreads();
        // suffix-inclusive scan: comb[t] = sum_{i>=t} c[i]
        for (int off = 1; off < 256; off <<= 1) {
            unsigned int v = 0;
            if (t < 256) v = (t + off < 256) ? comb[t + off] : 0u;
            __syncthreads();
            if (t < 256) comb[t] += v;
            __syncthreads();
        }
        int kcur = kk;                   // all threads read before any write
        unsigned int Sself = (t < 256) ? comb[t] : 0u;
        unsigned int Snext = (t < 255) ? comb[t + 1] : 0u;
        __syncthreads();
        if (t < 256) {
            // pick largest bin b with S[b+1] <= k < S[b]  (same as serial desc scan)
            if ((unsigned int)kcur < Sself && (unsigned int)kcur >= Snext) {
                prefix_s = pref | ((unsigned int)t << shift);
                kk = kcur - (int)Snext;
            }
        }
        __syncthreads();
    }
    if (t == 0) thrA[b] = __uint_as_float(prefix_s);
}

// ---------------- degree -> dis = rsqrt(deg) ----------------
__global__ void deg_kernel(const float* S, const float* thrA, float* dis) {
    int l = blockIdx.x, b = blockIdx.y, t = threadIdx.x; // 64
    __shared__ float red[64];
    float thr = thrA[b];
    const float* row = S + ((size_t)b * Ln + l) * Ln;
    int cnt = 0;
    for (int m = t; m < Ln; m += 64) if (m != l && row[m] > thr) cnt++;
    red[t] = (float)cnt; __syncthreads();
    for (int s = 32; s > 0; s >>= 1) { if (t < s) red[t] += red[t + s]; __syncthreads(); }
    if (t == 0) dis[b * Ln + l] = rsqrtf(red[0] + 1.f); // +1 self loop
}

// ---------------- An = A_bool * dis_l * dis_m (in-place over S) ----------------
__global__ void an_kernel(float* S, const float* thrA, const float* dis) {
    size_t idx = (size_t)blockIdx.x * 256 + threadIdx.x;
    if (idx >= (size_t)Bn * Ln * Ln) return;
    int b = (int)(idx / (Ln * Ln));
    int rem = (int)(idx % (Ln * Ln));
    int l = rem / Ln, m = rem % Ln;
    float ab = (l == m) ? 1.f : ((S[idx] > thrA[b]) ? 1.f : 0.f);
    S[idx] = ab * dis[b * Ln + l] * dis[b * Ln + m];
}

// ---------------- C = An @ M per batch (M staged in LDS) ----------------
__global__ __launch_bounds__(256) void an_mm2_kernel(const float* An, const float* M, float* C) {
    int b = blockIdx.x, t = threadIdx.x;
    __shared__ float Ml[200 * 128];    // 102.4 KB
    __shared__ float At[16 * 200];     // 12.8 KB
    const float4* src = (const float4*)(M + (size_t)b * Ln * Dn);
    for (int i = t; i < 6400; i += 256) ((float4*)Ml)[i] = src[i];
    int d0 = t & 63, rg = t >> 6;      // rg 0..3, rows rg*4..+3 within tile
    for (int rb = 0; rb < 13; ++rb) {
        int base = rb * 16;
        int nrows = (base + 16 <= Ln) ? 16 : (Ln - base);
        __syncthreads();               // protect At (and Ml on first iter)
        for (int i = t; i < nrows * 200; i += 256)
            At[i] = An[((size_t)b * Ln + base + i / 200) * Ln + (i % 200)];
        __syncthreads();
        if (rg * 4 < nrows) {
            float acc[4][2] = {{0,0},{0,0},{0,0},{0,0}};
            for (int m = 0; m < Ln; ++m) {
                float w0 = Ml[m * 128 + d0];
                float w1 = Ml[m * 128 + d0 + 64];
                #pragma unroll
                for (int ii = 0; ii < 4; ++ii) {
                    float a = At[(rg * 4 + ii) * 200 + m];
                    acc[ii][0] += a * w0;
                    acc[ii][1] += a * w1;
                }
            }
            #pragma unroll
            for (int ii = 0; ii < 4; ++ii) {
                size_t orow = (size_t)b * Ln + base + rg * 4 + ii;
                C[orow * 128 + d0] = acc[ii][0];
                C[orow * 128 + d0 + 64] = acc[ii][1];
            }
        }
    }
}

// ---------------- out = in @ W128 (+ optional residual & leaky relu) ----------------
template<int RES>
__global__ __launch_bounds__(512) void ai2_kernel(const float* in, const float* Wm,
                                                  float* out, const float* res) {
    __shared__ float Wl[128 * 128];    // 64 KB
    __shared__ float Rl[128 * 128];    // 64 KB
    int t = threadIdx.x;
    size_t row0 = (size_t)blockIdx.x * 128;
    const float4* wsrc = (const float4*)Wm;
    for (int i = t; i < 4096; i += 512) ((float4*)Wl)[i] = wsrc[i];
    const float4* rsrc = (const float4*)(in + row0 * 128);
    for (int i = t; i < 4096; i += 512) ((float4*)Rl)[i] = rsrc[i];
    __syncthreads();
    int d0 = t & 63, rg = t >> 6;      // 8 groups of 16 rows
    float acc[16][2];
    #pragma unroll
    for (int rr = 0; rr < 16; ++rr) { acc[rr][0] = 0.f; acc[rr][1] = 0.f; }
    for (int k = 0; k < 128; ++k) {
        float w0 = Wl[k * 128 + d0], w1 = Wl[k * 128 + d0 + 64];
        #pragma unroll
        for (int rr = 0; rr < 16; ++rr) {
            float x = Rl[(rg * 16 + rr) * 128 + k];
            acc[rr][0] += x * w0;
            acc[rr][1] += x * w1;
        }
    }
    #pragma unroll
    for (int rr = 0; rr < 16; ++rr) {
        size_t orow = row0 + rg * 16 + rr;
        float v0 = acc[rr][0], v1 = acc[rr][1];
        if (RES) {
            v0 = lrelu(v0 + res[orow * 128 + d0]);
            v1 = lrelu(v1 + res[orow * 128 + d0 + 64]);
        }
        out[orow * 128 + d0] = v0;
        out[orow * 128 + d0 + 64] = v1;
    }
}

// ---------------- attn fc0: z0 = [ai,q,ai-q,ai*q] @ w0 + b0, fused BN stats ----------------
__global__ __launch_bounds__(256) void fc02_kernel(const float* ai, const float* query, int q3d,
                                                   const float* w0, const float* b0,
                                                   float* z0, float* stats0) {
    __shared__ float F[64 * 129];      // 33 KB feature chunk (padded)
    __shared__ float W[128 * 80];      // 40 KB weight chunk
    __shared__ float sums[160];
    int t = threadIdx.x;
    size_t row0 = (size_t)blockIdx.x * 64;
    float areg[32], qreg[32];
    #pragma unroll
    for (int j = 0; j < 32; ++j) {
        int i = t + j * 256;
        int r = i >> 7, k = i & 127;
        size_t grow = row0 + r;
        areg[j] = ai[grow * 128 + k];
        qreg[j] = q3d ? query[grow * 128 + k] : query[(grow / Ln) * 128 + k];
    }
    int r0 = (t & 31) * 2, cg = t >> 5;  // cols cg*10 + j
    float acc[2][10];
    #pragma unroll
    for (int j = 0; j < 10; ++j) { acc[0][j] = 0.f; acc[1][j] = 0.f; }
    for (int c = 0; c < 4; ++c) {
        if (c) __syncthreads();          // previous chunk's readers done
        #pragma unroll
        for (int j = 0; j < 32; ++j) {
            int i = t + j * 256;
            int r = i >> 7, k = i & 127;
            float a = areg[j], q = qreg[j];
            float f = (c == 0) ? a : (c == 1) ? q : (c == 2) ? (a - q) : (a * q);
            F[r * 129 + k] = f;
        }
        for (int i = t; i < 10240; i += 256) W[i] = w0[c * 10240 + i];
        __syncthreads();
        for (int k = 0; k < 128; ++k) {
            float f0 = F[r0 * 129 + k], f1v = F[(r0 + 1) * 129 + k];
            #pragma unroll
            for (int j = 0; j < 10; ++j) {
                float w = W[k * 80 + cg * 10 + j];
                acc[0][j] += f0 * w;
                acc[1][j] += f1v * w;
            }
        }
    }
    __syncthreads();
    if (t < 160) sums[t] = 0.f;
    __syncthreads();
    #pragma unroll
    for (int j = 0; j < 10; ++j) {
        float bb = b0[cg * 10 + j];
        float z0v = acc[0][j] + bb;
        float z1v = acc[1][j] + bb;
        z0[(row0 + r0) * 80 + cg * 10 + j] = z0v;
        z0[(row0 + r0 + 1) * 80 + cg * 10 + j] = z1v;
        atomicAdd(&sums[cg * 10 + j], z0v + z1v);
        atomicAdd(&sums[80 + cg * 10 + j], z0v * z0v + z1v * z1v);
    }
    __syncthreads();
    if (t < 80) {
        atomicAdd(&stats0[t], sums[t]);
        atomicAdd(&stats0[80 + t], sums[80 + t]);
    }
}

// ---------------- attn fc1: BN(z0)->relu -> @w1 + b1, fused BN stats ----------------
__global__ __launch_bounds__(256) void fc1b_kernel(const float* z0, const float* stats0,
                                                   const float* g0, const float* be0,
                                                   const float* w1, const float* b1,
                                                   float* z1, float* stats1, int N) {
    __shared__ float Y[64 * 81];
    __shared__ float W1s[80 * 40];
    __shared__ float mnA[80], rsA[80], gA[80], beA[80];
    __shared__ float sums[80];
    int t = threadIdx.x;
    size_t row0 = (size_t)blockIdx.x * 64;
    if (t < 80) {
        float mean = stats0[t] / N;
        float var = stats0[80 + t] / N - mean * mean;
        mnA[t] = mean; rsA[t] = rsqrtf(var + EPS); gA[t] = g0[t]; beA[t] = be0[t];
    }
    for (int i = t; i < 3200; i += 256) W1s[i] = w1[i];
    __syncthreads();
    for (int i = t; i < 5120; i += 256) {
        int r = i / 80, k = i % 80;
        float v = z0[row0 * 80 + i];
        float y = (v - mnA[k]) * rsA[k] * gA[k] + beA[k];
        Y[r * 81 + k] = fmaxf(y, 0.f);
    }
    __syncthreads();
    int r0 = (t & 31) * 2, cg = t >> 5;  // cols cg*5 + j
    float acc[2][5];
    #pragma unroll
    for (int j = 0; j < 5; ++j) { acc[0][j] = 0.f; acc[1][j] = 0.f; }
    for (int k = 0; k < 80; ++k) {
        float y0 = Y[r0 * 81 + k], y1 = Y[(r0 + 1) * 81 + k];
        #pragma unroll
        for (int j = 0; j < 5; ++j) {
            float w = W1s[k * 40 + cg * 5 + j];
            acc[0][j] += y0 * w;
            acc[1][j] += y1 * w;
        }
    }
    __syncthreads();
    if (t < 80) sums[t] = 0.f;
    __syncthreads();
    #pragma unroll
    for (int j = 0; j < 5; ++j) {
        float bb = b1[cg * 5 + j];
        float z0v = acc[0][j] + bb;
        float z1v = acc[1][j] + bb;
        z1[(row0 + r0) * 40 + cg * 5 + j] = z0v;
        z1[(row0 + r0 + 1) * 40 + cg * 5 + j] = z1v;
        atomicAdd(&sums[cg * 5 + j], z0v + z1v);
        atomicAdd(&sums[40 + cg * 5 + j], z0v * z0v + z1v * z1v);
    }
    __syncthreads();
    if (t < 40) {
        atomicAdd(&stats1[t], sums[t]);
        atomicAdd(&stats1[40 + t], sums[40 + t]);
    }
}

// ---------------- attn out: o = relu(BN(z1)) @ wo + bo ----------------
__global__ __launch_bounds__(256) void out2_kernel(const float* z1, const float* stats1,
                                                   const float* g1, const float* be1,
                                                   const float* wo, const float* bo,
                                                   float* o, int N) {
    __shared__ float Zs[256 * 41];
    __shared__ float mnA[40], rsA[40], gA[40], beA[40], woA[40];
    int t = threadIdx.x;
    size_t row0 = (size_t)blockIdx.x * 256;
    if (t < 40) {
        float mean = stats1[t] / N;
        float var = stats1[40 + t] / N - mean * mean;
        mnA[t] = mean; rsA[t] = rsqrtf(var + EPS);
        gA[t] = g1[t]; beA[t] = be1[t]; woA[t] = wo[t];
    }
    __syncthreads();
    for (int i = t; i < 10240; i += 256) {
        int r = i / 40, k = i % 40;
        float v = z1[row0 * 40 + i];
        float y = (v - mnA[k]) * rsA[k] * gA[k] + beA[k];
        Zs[r * 41 + k] = fmaxf(y, 0.f);
    }
    __syncthreads();
    float acc = bo[0];
    for (int k = 0; k < 40; ++k) acc += Zs[t * 41 + k] * woA[k];
    o[row0 + t] = acc;
}

// softmax over L with mask; optional second addend; optional *mask on output
__global__ void masked_softmax_kernel(const float* o, const float* o2, const float* mask,
                                      float neg, int mulmask, float* w) {
    int b = blockIdx.x, t = threadIdx.x; // 256
    __shared__ float buf[Ln];
    __shared__ float red[256];
    if (t < Ln) {
        float x = o[b * Ln + t];
        if (o2) x += o2[b * Ln + t];
        buf[t] = (mask[b * Ln + t] > 0.f) ? x : neg;
    }
    __syncthreads();
    red[t] = (t < Ln) ? buf[t] : -3.4e38f;
    __syncthreads();
    for (int s = 128; s > 0; s >>= 1) { if (t < s) red[t] = fmaxf(red[t], red[t + s]); __syncthreads(); }
    float mx = red[0];
    __syncthreads();
    float e = 0.f;
    if (t < Ln) e = expf(buf[t] - mx);
    red[t] = e;
    __syncthreads();
    for (int s = 128; s > 0; s >>= 1) { if (t < s) red[t] += red[t + s]; __syncthreads(); }
    float sm = red[0];
    if (t < Ln) {
        float v = e / sm;
        if (mulmask) v *= mask[b * Ln + t];
        w[b * Ln + t] = v;
    }
}

// ---------------- E row-softmax + ex = P @ X (per batch) ----------------
__global__ __launch_bounds__(256) void fxc_p_kernel(const float* An, const float* f1, const float* f2,
                                                    const float* X, float* ex) {
    __shared__ float Xl[200 * 128];    // 102.4 KB
    __shared__ float p[4][200];
    __shared__ float invs[4];
    __shared__ float f1s[200];
    int b = blockIdx.x, t = threadIdx.x;
    const float4* src = (const float4*)(X + (size_t)b * Ln * Dn);
    for (int i = t; i < 6400; i += 256) ((float4*)Xl)[i] = src[i];
    for (int i = t; i < 200; i += 256) f1s[i] = f1[b * Ln + i];
    __syncthreads();
    int wv = t >> 6, lane = t & 63;
    for (int l0 = 0; l0 < Ln; l0 += 4) {
        int l = l0 + wv;
        float f2l = f2[b * Ln + l];
        const float* Arow = An + ((size_t)b * Ln + l) * Ln;
        float e[4]; float mx = -3.4e38f;
        #pragma unroll
        for (int j = 0; j < 4; ++j) {
            int m = lane + 64 * j;
            float ev = NEGINF;
            if (m < Ln) {
                float ab = Arow[m];
                if (ab > 0.f) { float s = f1s[m] + f2l; ev = (s > 0.f) ? s : 0.01f * s; }
            }
            e[j] = ev; mx = fmaxf(mx, ev);
        }
        for (int off = 32; off > 0; off >>= 1) mx = fmaxf(mx, __shfl_xor(mx, off));
        float sm = 0.f;
        #pragma unroll
        for (int j = 0; j < 4; ++j) {
            int m = lane + 64 * j;
            float pe = (m < Ln) ? expf(e[j] - mx) : 0.f;
            if (m < Ln) p[wv][m] = pe;
            sm += pe;
        }
        for (int off = 32; off > 0; off >>= 1) sm += __shfl_xor(sm, off);
        if (lane == 0) invs[wv] = 1.f / sm;
        __syncthreads();
        int d0 = lane * 2;
        float a0 = 0.f, a1 = 0.f;
        const float* pr = p[wv];
        for (int m = 0; m < Ln; ++m) {
            float pm = pr[m];
            float2 x2 = *(const float2*)&Xl[m * 128 + d0];
            a0 += pm * x2.x;
            a1 += pm * x2.y;
        }
        float inv = invs[wv];
        size_t orow = (size_t)b * Ln + l;
        ex[orow * 128 + d0] = a0 * inv;
        ex[orow * 128 + d0 + 1] = a1 * inv;
        __syncthreads();
    }
}

// ---------------- pooling: mask2 = cs > (k-th largest), order, red_len ----------------
__global__ void pool_kernel(const float* cs, const int* his_len, float* mask2,
                            int* order, int* red_len) {
    int b = blockIdx.x, t = threadIdx.x; // 256
    __shared__ float v[Ln];
    __shared__ float thr;
    if (t < Ln) v[t] = cs[b * Ln + t];
    __syncthreads();
    int k = min(his_len[b], POOLN);
    if (t < Ln) {
        float x = v[t];
        int gt = 0, eq = 0;
        for (int i = 0; i < Ln; ++i) { gt += (v[i] > x); eq += (v[i] == x); }
        if (gt <= k && k < gt + eq) thr = x; // the k-th order statistic (desc)
    }
    __syncthreads();
    if (t < Ln) mask2[b * Ln + t] = (v[t] > thr) ? 1.f : 0.f;
    __syncthreads();
    if (t == 0) {
        int idx = 0;
        for (int l = 0; l < Ln; ++l) if (v[l] > thr) order[b * Ln + idx++] = l;
        red_len[b] = idx;
        for (int l = 0; l < Ln; ++l) if (!(v[l] > thr)) order[b * Ln + idx++] = l;
    }
}

__global__ void readout_kernel(const float* Xc, const float* cs, const float* mask2, float* gr) {
    int b = blockIdx.x, t = threadIdx.x; // 128
    float acc = 0.f;
    for (int l = 0; l < Ln; ++l)
        acc += Xc[((size_t)b * Ln + l) * Dn + t] * cs[b * Ln + l] * mask2[b * Ln + l];
    gr[b * Dn + t] = acc;
}

__global__ void gather_kernel(const float* Xc, const float* mask2, const int* order,
                              float* Xs, float* mask_s) {
    int i = blockIdx.x, b = blockIdx.y, t = threadIdx.x; // 128
    int src = order[b * Ln + i];
    Xs[((size_t)b * Ln + i) * Dn + t] = Xc[((size_t)b * Ln + src) * Dn + t];
    if (t == 0) mask_s[b * Ln + i] = mask2[b * Ln + src];
}

// ---------------- AUGRU ----------------
__global__ void xp_kernel(const float* Xs, const float* Wx, const float* bx, float* xp) {
    int l = blockIdx.x, b = blockIdx.y, t = threadIdx.x; // 384
    __shared__ float x[Dn];
    if (t < Dn) x[t] = Xs[((size_t)b * Ln + l) * Dn + t];
    __syncthreads();
    float acc = bx[t];
    for (int d = 0; d < Dn; ++d) acc += x[d] * Wx[d * 384 + t];
    xp[((size_t)b * POOLN + l) * 384 + t] = acc;
}

__global__ void augru_kernel(const float* xp, const float* alphas, const int* red_len,
                             const float* Wh, const float* bh, float* final_h) {
    int b = blockIdx.x, j = threadIdx.x; // 128
    __shared__ float h[Hn];
    h[j] = 0.f;
    __syncthreads();
    int T = red_len[b];
    for (int step = 0; step < T; ++step) {
        float hr = bh[j], hu = bh[Hn + j], hn = bh[2 * Hn + j];
        for (int k = 0; k < Hn; ++k) {
            float hk = h[k];
            hr += hk * Wh[k * 384 + j];
            hu += hk * Wh[k * 384 + Hn + j];
            hn += hk * Wh[k * 384 + 2 * Hn + j];
        }
        const float* xrow = xp + ((size_t)b * POOLN + step) * 384;
        float a = alphas[b * Ln + step];
        float r = sigmoidf(xrow[j] + hr);
        float u = sigmoidf(xrow[Hn + j] + hu) * a;
        float n = tanhf(xrow[2 * Hn + j] + r * hn);
        float hnew = (1.f - u) * h[j] + u * n;
        __syncthreads();
        h[j] = hnew;
        __syncthreads();
    }
    final_h[b * Hn + j] = h[j];
}

// ---------------- head ----------------
__global__ void mo_kernel(const float* final_h, const float* gr, const float* tgt, float* mo) {
    int b = blockIdx.x, t = threadIdx.x; // 128
    mo[b * 512 + t] = final_h[b * Hn + t];
    mo[b * 512 + 128 + t] = gr[b * Dn + t];
    mo[b * 512 + 256 + t] = tgt[b * Dn + t];
    mo[b * 512 + 384 + t] = gr[b * Dn + t] * tgt[b * Dn + t];
}

// stats[c] = sum, stats[C+c] = sumsq.  blockDim=(C,TY)
__global__ void bn_stats_kernel(const float* z, int N, int C, float* stats) {
    int c = threadIdx.x;
    extern __shared__ float red[]; // 2*C*TY
    float s = 0.f, q = 0.f;
    for (int r = blockIdx.x * blockDim.y + threadIdx.y; r < N; r += gridDim.x * blockDim.y) {
        float v = z[(size_t)r * C + c];
        s += v; q += v * v;
    }
    red[threadIdx.y * C + c] = s;
    red[blockDim.y * C + threadIdx.y * C + c] = q;
    __syncthreads();
    if (threadIdx.y == 0) {
        for (int ty = 1; ty < (int)blockDim.y; ++ty) {
            s += red[ty * C + c];
            q += red[blockDim.y * C + ty * C + c];
        }
        atomicAdd(&stats[c], s);
        atomicAdd(&stats[C + c], q);
    }
}

// generic dense layer: optional BN+relu on input, then y = in' @ w + bias
__global__ void head_fc_kernel(const float* in, int K, int C, const float* w, const float* bias,
                               const float* stats, int statN, const float* g, const float* be,
                               float* out) {
    int b = blockIdx.x;
    extern __shared__ float y[]; // K floats
    for (int k = threadIdx.x; k < K; k += blockDim.x) {
        float v = in[(size_t)b * K + k];
        if (stats) {
            float mean = stats[k] / statN;
            float var = stats[K + k] / statN - mean * mean;
            v = fmaxf((v - mean) * rsqrtf(var + EPS) * g[k] + be[k], 0.f);
        }
        y[k] = v;
    }
    __syncthreads();
    for (int c = threadIdx.x; c < C; c += blockDim.x) {
        float acc = bias[c];
        for (int k = 0; k < K; ++k) acc += y[k] * w[k * C + c];
        out[(size_t)b * C + c] = acc;
    }
}

// ---------------- host driver ----------------
struct AttnParams {
    const float *w0, *b0, *g0, *be0, *w1, *b1, *g1, *be1, *wo, *bo;
};

static void run_attn_fcn(hipStream_t stream, const float* kv, const float* query, int q3d,
                         const float* mat, const float* mask, const AttnParams& P,
                         float* ai, float* z0, float* z1, float* o,
                         float* stats0, float* stats1, float* out_w) {
    ai2_kernel<0><<<400, 512, 0, stream>>>(kv, mat, ai, nullptr);
    hipMemsetAsync(stats0, 0, 160 * sizeof(float), stream);
    fc02_kernel<<<800, 256, 0, stream>>>(ai, query, q3d, P.w0, P.b0, z0, stats0);
    hipMemsetAsync(stats1, 0, 80 * sizeof(float), stream);
    fc1b_kernel<<<800, 256, 0, stream>>>(z0, stats0, P.g0, P.be0, P.w1, P.b1, z1, stats1, Bn * Ln);
    out2_kernel<<<200, 256, 0, stream>>>(z1, stats1, P.g1, P.be1, P.wo, P.bo, o, Bn * Ln);
    masked_softmax_kernel<<<Bn, 256, 0, stream>>>(o, nullptr, mask, NEGINF, 0, out_w);
}

extern "C" void kernel_launch(void* const* d_in, const int* in_sizes, int n_in,
                              void* d_out, int out_size, void* d_ws, size_t ws_size,
                              hipStream_t stream) {
    (void)in_sizes; (void)n_in; (void)out_size; (void)ws_size;
    const int* his_pro = (const int*)d_in[0];
    const int* his_y   = (const int*)d_in[1];
    const int* his_len = (const int*)d_in[2];
    const int* cur_pro = (const int*)d_in[3];
    const float* item_emb    = (const float*)d_in[5];
    const float* ans_emb     = (const float*)d_in[6];
    const float* wt          = (const float*)d_in[7];
    const float* att_cluster = (const float*)d_in[8];
    const float* att_query   = (const float*)d_in[9];
    const float* att_rnn     = (const float*)d_in[10];
    const float* aggre_W     = (const float*)d_in[11];
    const float* gru_Wx = (const float*)d_in[12];
    const float* gru_Wh = (const float*)d_in[13];
    const float* gru_bx = (const float*)d_in[14];
    const float* gru_bh = (const float*)d_in[15];
    AttnParams AP;
    AP.w0 = (const float*)d_in[16]; AP.b0 = (const float*)d_in[17];
    AP.g0 = (const float*)d_in[18]; AP.be0 = (const float*)d_in[19];
    AP.w1 = (const float*)d_in[20]; AP.b1 = (const float*)d_in[21];
    AP.g1 = (const float*)d_in[22]; AP.be1 = (const float*)d_in[23];
    AP.wo = (const float*)d_in[24]; AP.bo = (const float*)d_in[25];
    const float* t_w0 = (const float*)d_in[26];
    const float* t_b0 = (const float*)d_in[27];
    const float* t_g0 = (const float*)d_in[28];
    const float* t_be0 = (const float*)d_in[29];
    const float* t_w1 = (const float*)d_in[30];
    const float* t_b1 = (const float*)d_in[31];
    const float* t_g1 = (const float*)d_in[32];
    const float* t_be1 = (const float*)d_in[33];
    const float* t_wo = (const float*)d_in[34];
    const float* t_bo = (const float*)d_in[35];

    // -------- workspace carve --------
    char* p = (char*)d_ws;
    auto alloc = [&](size_t bytes) -> void* {
        void* r = (void*)p;
        p += ((bytes + 255) / 256) * 256;
        return r;
    };
    const size_t NX = (size_t)Bn * Ln * Dn;
    const size_t NS = (size_t)Bn * Ln * Ln;
    float* X    = (float*)alloc(NX * 4);
    float* XfXc = (float*)alloc(NX * 4);   // Xf, later reused as Xc
    float* S    = (float*)alloc(NS * 4);   // S raw -> scaled -> An in-place
    float* tmp  = (float*)alloc(NX * 4);   // An@M temp / attn 'ai' / ex
    float* XqXs = (float*)alloc(NX * 4);   // Xq, later Xs
    float* z0   = (float*)alloc((size_t)Bn * Ln * C0 * 4);
    float* z1   = (float*)alloc((size_t)Bn * Ln * C1 * 4);
    float* obuf = (float*)alloc((size_t)Bn * Ln * 4);
    float* f1   = (float*)alloc((size_t)Bn * Ln * 4);
    float* f2   = (float*)alloc((size_t)Bn * Ln * 4);
    float* alph = (float*)alloc((size_t)Bn * Ln * 4);
    float* mask = (float*)alloc((size_t)Bn * Ln * 4);
    float* tgt  = (float*)alloc((size_t)Bn * Dn * 4);
    float* dis  = (float*)alloc((size_t)Bn * Ln * 4);
    float* thrA = (float*)alloc((size_t)Bn * 4);
    int*   nedges = (int*)alloc((size_t)Bn * 4);
    float* rowmin = (float*)alloc((size_t)Bn * Ln * 4);
    float* rowmax = (float*)alloc((size_t)Bn * Ln * 4);
    float* statsA = (float*)alloc(2 * 200 * 4);
    float* statsB = (float*)alloc(2 * 200 * 4);
    float* cs     = (float*)alloc((size_t)Bn * Ln * 4);
    float* mask2  = (float*)alloc((size_t)Bn * Ln * 4);
    int*   order  = (int*)alloc((size_t)Bn * Ln * 4);
    int*   redlen = (int*)alloc((size_t)Bn * 4);
    float* mask_s = (float*)alloc((size_t)Bn * Ln * 4);
    float* xp     = (float*)alloc((size_t)Bn * POOLN * 384 * 4);
    float* finalh = (float*)alloc((size_t)Bn * Hn * 4);
    float* gr     = (float*)alloc((size_t)Bn * Dn * 4);
    float* mo     = (float*)alloc((size_t)Bn * 512 * 4);
    float* t0buf  = (float*)alloc((size_t)Bn * T0 * 4);
    float* t1buf  = (float*)alloc((size_t)Bn * T1 * 4);

    dim3 gLB(Ln, Bn);

    // ---- inputs ----
    build_x_kernel<<<gLB, 128, 0, stream>>>(his_pro, his_y, item_emb, ans_emb, X);
    build_tgt_mask_kernel<<<Bn, 256, 0, stream>>>(cur_pro, his_len, item_emb, tgt, mask);

    // ---- similarity graph ----
    xf_kernel<<<gLB, 128, 0, stream>>>(X, wt, XfXc);
    s2_gemm_kernel<<<Bn, 256, 0, stream>>>(XfXc, S, rowmin, rowmax);
    s2_scale_kernel<<<Bn, 256, 0, stream>>>(S, rowmin, rowmax, mask, nedges);
    radix_select2_kernel<<<Bn, 1024, 0, stream>>>(S, nedges, thrA);
    deg_kernel<<<gLB, 64, 0, stream>>>(S, thrA, dis);
    an_kernel<<<(int)((NS + 255) / 256), 256, 0, stream>>>(S, thrA, dis); // S -> An

    // ---- fusion round 1 ----
    an_mm2_kernel<<<Bn, 256, 0, stream>>>(S, X, tmp);
    an_mm2_kernel<<<Bn, 256, 0, stream>>>(S, tmp, XqXs); // Xq
    run_attn_fcn(stream, X, XqXs, 1, att_cluster, mask, AP, tmp, z0, z1, obuf, statsA, statsB, f1);
    run_attn_fcn(stream, X, tgt, 0, att_query, mask, AP, tmp, z0, z1, obuf, statsA, statsB, f2);
    fxc_p_kernel<<<Bn, 256, 0, stream>>>(S, f1, f2, X, tmp);       // ex -> tmp
    ai2_kernel<1><<<400, 512, 0, stream>>>(tmp, aggre_W, XfXc, X); // Xc = lrelu(ex@W + X)

    // ---- fusion round 2 (extraction) ----
    an_mm2_kernel<<<Bn, 256, 0, stream>>>(S, XfXc, tmp);
    an_mm2_kernel<<<Bn, 256, 0, stream>>>(S, tmp, XqXs); // Xq2
    run_attn_fcn(stream, XfXc, XqXs, 1, att_cluster, mask, AP, tmp, z0, z1, obuf, statsA, statsB, f1);
    run_attn_fcn(stream, XfXc, tgt, 0, att_query, mask, AP, tmp, z0, z1, obuf, statsA, statsB, f2);
    masked_softmax_kernel<<<Bn, 256, 0, stream>>>(f1, f2, mask, NEGBIG, 1, cs);

    // ---- pooling ----
    pool_kernel<<<Bn, 256, 0, stream>>>(cs, his_len, mask2, order, redlen);
    readout_kernel<<<Bn, 128, 0, stream>>>(XfXc, cs, mask2, gr);
    gather_kernel<<<gLB, 128, 0, stream>>>(XfXc, mask2, order, XqXs, mask_s); // Xs

    // ---- AUGRU ----
    run_attn_fcn(stream, XqXs, tgt, 0, att_rnn, mask_s, AP, tmp, z0, z1, obuf, statsA, statsB, alph);
    xp_kernel<<<dim3(POOLN, Bn), 384, 0, stream>>>(XqXs, gru_Wx, gru_bx, xp);
    augru_kernel<<<Bn, 128, 0, stream>>>(xp, alph, redlen, gru_Wh, gru_bh, finalh);

    // ---- head ----
    mo_kernel<<<Bn, 128, 0, stream>>>(finalh, gr, tgt, mo);
    head_fc_kernel<<<Bn, 256, 512 * 4, stream>>>(mo, 512, T0, t_w0, t_b0,
                                                 nullptr, 0, nullptr, nullptr, t0buf);
    hipMemsetAsync(statsA, 0, 2 * T0 * sizeof(float), stream);
    bn_stats_kernel<<<32, dim3(T0, 1), 2 * T0 * sizeof(float), stream>>>(t0buf, Bn, T0, statsA);
    head_fc_kernel<<<Bn, 256, T0 * 4, stream>>>(t0buf, T0, T1, t_w1, t_b1,
                                                statsA, Bn, t_g0, t_be0, t1buf);
    hipMemsetAsync(statsB, 0, 2 * T1 * sizeof(float), stream);
    bn_stats_kernel<<<16, dim3(T1, 3), 2 * T1 * 3 * sizeof(float), stream>>>(t1buf, Bn, T1, statsB);
    head_fc_kernel<<<Bn, 256, T1 * 4, stream>>>(t1buf, T1, 1, t_wo, t_bo,
                                                statsB, Bn, t_g1, t_be1, (float*)d_out);
}

// Round 11
// 2601.786 us; speedup vs baseline: 2.0587x; 1.0512x over previous
//
#include <hip/hip_runtime.h>
#include <math.h>

// ---------------- constants ----------------
constexpr int Bn = 256;    // batch
constexpr int Ln = 200;    // seq len
constexpr int Dn = 128;    // node dim
constexpr int Hn = 128;    // AUGRU hidden
constexpr int C0 = 80;     // attn fc0 width
constexpr int C1 = 40;     // attn fc1 width
constexpr int T0 = 200;    // task fc0 width
constexpr int T1 = 80;     // task fc1 width
constexpr int POOLN = 30;
constexpr float EPS = 1e-4f;
constexpr float NEGINF = -1e30f;
constexpr float NEGBIG = -4294967295.0f;

__device__ __forceinline__ float lrelu(float x) { return x > 0.f ? x : 0.01f * x; }
__device__ __forceinline__ float sigmoidf(float x) { return 1.f / (1.f + expf(-x)); }
// order-preserving float<->int key for atomic min/max
__device__ __forceinline__ int fkey(float f) { int i = __float_as_int(f); return i < 0 ? (i ^ 0x7fffffff) : i; }
__device__ __forceinline__ float funkey(int k) { return __int_as_float(k < 0 ? (k ^ 0x7fffffff) : k); }

// ---------------- build X, tgt, mask ----------------
__global__ void build_x_kernel(const int* his_pro, const int* his_y,
                               const float* item_emb, const float* ans_emb, float* X) {
    int l = blockIdx.x, b = blockIdx.y, t = threadIdx.x; // 128 threads
    size_t row = ((size_t)b * Ln + l) * Dn;
    if (t < 64) X[row + t] = item_emb[(size_t)his_pro[b * Ln + l] * 64 + t];
    else        X[row + t] = ans_emb[his_y[b * Ln + l] * 64 + (t - 64)];
}

__global__ void build_tgt_mask_kernel(const int* cur_pro, const int* his_len,
                                      const float* item_emb, float* tgt, float* mask) {
    int b = blockIdx.x, t = threadIdx.x; // 256 threads
    if (t < 64) tgt[b * Dn + t] = item_emb[(size_t)cur_pro[b] * 64 + t];
    else if (t < 128) tgt[b * Dn + t] = 0.f;
    if (t < Ln) mask[b * Ln + t] = (t < his_len[b]) ? 1.f : 0.f;
}

// ---------------- Xf = normalize(X * w) ----------------
__global__ void xf_kernel(const float* X, const float* wt, float* Xf) {
    int l = blockIdx.x, b = blockIdx.y, t = threadIdx.x; // 128
    __shared__ float red[128];
    size_t row = ((size_t)b * Ln + l) * Dn;
    float v = X[row + t] * wt[t];
    red[t] = v * v;
    __syncthreads();
    for (int s = 64; s > 0; s >>= 1) { if (t < s) red[t] += red[t + s]; __syncthreads(); }
    float norm = fmaxf(sqrtf(red[0]), 1e-12f);
    Xf[row + t] = v / norm;
}

// ---------------- S = Xf Xf^T per batch (raw dots) + per-row min/max ----------------
__global__ __launch_bounds__(256) void s2_gemm_kernel(const float* Xf, float* S,
                                                      float* rowmin, float* rowmax) {
    int b = blockIdx.x, t = threadIdx.x;
    __shared__ float Xl[208 * 132];      // padded rows (200..207 garbage, never stored)
    __shared__ int mnI[200], mxI[200];
    const float4* src = (const float4*)(Xf + (size_t)b * Ln * Dn);
    for (int i = t; i < 6400; i += 256) {
        int row = i >> 5, c4 = i & 31;
        *(float4*)&Xl[row * 132 + c4 * 4] = src[i];
    }
    for (int i = t; i < 200; i += 256) { mnI[i] = 0x7fffffff; mxI[i] = (int)0x80000000; }
    __syncthreads();
    int ty = t >> 4, tx = t & 15;
    float* Sb = S + (size_t)b * Ln * Ln;
    // main region: rows pairs (ri=2rg,2rg+1), cols groups of 4 (ci=4cg..4cg+3)
    for (int rg = 0; rg < 6; ++rg) {
        int l0 = ty + 32 * rg, l1 = l0 + 16;            // both < 192+16 -> <=191, valid
        for (int cg = 0; cg < 3; ++cg) {
            int m0 = tx + 64 * cg;                       // cols m0 + 16j, j<4, all <=191
            float acc[2][4] = {{0,0,0,0},{0,0,0,0}};
            for (int k = 0; k < 128; ++k) {
                float a0 = Xl[l0 * 132 + k], a1 = Xl[l1 * 132 + k];
                float b0 = Xl[(m0) * 132 + k];
                float b1 = Xl[(m0 + 16) * 132 + k];
                float b2 = Xl[(m0 + 32) * 132 + k];
                float b3 = Xl[(m0 + 48) * 132 + k];
                acc[0][0] += a0 * b0; acc[0][1] += a0 * b1; acc[0][2] += a0 * b2; acc[0][3] += a0 * b3;
                acc[1][0] += a1 * b0; acc[1][1] += a1 * b1; acc[1][2] += a1 * b2; acc[1][3] += a1 * b3;
            }
            #pragma unroll
            for (int rr = 0; rr < 2; ++rr) {
                int l = rr ? l1 : l0;
                float mn4 = fminf(fminf(acc[rr][0], acc[rr][1]), fminf(acc[rr][2], acc[rr][3]));
                float mx4 = fmaxf(fmaxf(acc[rr][0], acc[rr][1]), fmaxf(acc[rr][2], acc[rr][3]));
                atomicMin(&mnI[l], fkey(mn4));
                atomicMax(&mxI[l], fkey(mx4));
                #pragma unroll
                for (int j = 0; j < 4; ++j) Sb[l * Ln + m0 + 16 * j] = acc[rr][j];
            }
        }
        // col edge: m = tx + 192 (valid iff tx < 8)
        {
            int m = tx + 192;
            float a0 = 0.f, a1 = 0.f;
            for (int k = 0; k < 128; ++k) {
                float bv = Xl[m * 132 + k];
                a0 += Xl[l0 * 132 + k] * bv;
                a1 += Xl[l1 * 132 + k] * bv;
            }
            if (m < 200) {
                Sb[l0 * Ln + m] = a0;
                Sb[l1 * Ln + m] = a1;
                atomicMin(&mnI[l0], fkey(a0)); atomicMax(&mxI[l0], fkey(a0));
                atomicMin(&mnI[l1], fkey(a1)); atomicMax(&mxI[l1], fkey(a1));
            }
        }
    }
    // row edge: l = ty + 192 (valid iff ty < 8)
    {
        int l = ty + 192;
        for (int cg = 0; cg < 3; ++cg) {
            int m0 = tx + 64 * cg;
            float acc[4] = {0,0,0,0};
            for (int k = 0; k < 128; ++k) {
                float a = Xl[l * 132 + k];
                acc[0] += a * Xl[(m0) * 132 + k];
                acc[1] += a * Xl[(m0 + 16) * 132 + k];
                acc[2] += a * Xl[(m0 + 32) * 132 + k];
                acc[3] += a * Xl[(m0 + 48) * 132 + k];
            }
            if (l < 200) {
                float mn4 = fminf(fminf(acc[0], acc[1]), fminf(acc[2], acc[3]));
                float mx4 = fmaxf(fmaxf(acc[0], acc[1]), fmaxf(acc[2], acc[3]));
                atomicMin(&mnI[l], fkey(mn4));
                atomicMax(&mxI[l], fkey(mx4));
                #pragma unroll
                for (int j = 0; j < 4; ++j) Sb[l * Ln + m0 + 16 * j] = acc[j];
            }
        }
        int m = tx + 192;
        float a0 = 0.f;
        for (int k = 0; k < 128; ++k) a0 += Xl[l * 132 + k] * Xl[m * 132 + k];
        if (l < 200 && m < 200) {
            Sb[l * Ln + m] = a0;
            atomicMin(&mnI[l], fkey(a0)); atomicMax(&mxI[l], fkey(a0));
        }
    }
    __syncthreads();
    for (int i = t; i < 200; i += 256) {
        rowmin[b * Ln + i] = funkey(mnI[i]);
        rowmax[b * Ln + i] = funkey(mxI[i]);
    }
}

// ---------------- in-place scale + mask + edge count ----------------
__global__ __launch_bounds__(256) void s2_scale_kernel(float* S, const float* rowmin,
                                                       const float* rowmax, const float* mask,
                                                       int* nedges) {
    int b = blockIdx.x, t = threadIdx.x;
    __shared__ float mn_s[200], mx_s[200], mk[200];
    __shared__ int red[256];
    for (int i = t; i < 200; i += 256) {
        mn_s[i] = rowmin[b * Ln + i];
        mx_s[i] = rowmax[b * Ln + i];
        mk[i] = mask[b * Ln + i];
    }
    __syncthreads();
    float* Sb = S + (size_t)b * Ln * Ln;
    int cnt = 0;
    for (int idx = t; idx < Ln * Ln; idx += 256) {
        int r = idx / Ln, c = idx % Ln;
        float v = Sb[idx];
        float mn = mn_s[r], d = mx_s[r] - mn;
        float sc = (d > 0.f) ? (v - mn) / d : 0.f;   // nan_to_num(0/0)=0
        sc *= mk[r] * mk[c];
        cnt += (sc != 0.f);
        Sb[idx] = sc;
    }
    red[t] = cnt;
    __syncthreads();
    for (int s = 128; s > 0; s >>= 1) { if (t < s) red[t] += red[t + s]; __syncthreads(); }
    if (t == 0) nedges[b] = red[0];
}

// ---------------- exact k-th largest via radix select (v2) ----------------
// 1024 threads, per-wave privatized histograms, parallel suffix scan.
__global__ __launch_bounds__(1024) void radix_select2_kernel(const float* S, const int* nedges,
                                                             float* thrA) {
    int b = blockIdx.x, t = threadIdx.x;
    int wv = t >> 6;                      // 16 waves
    __shared__ unsigned int hist[16][256]; // 16 KB
    __shared__ unsigned int comb[256];
    __shared__ unsigned int prefix_s;
    __shared__ int kk;
    const unsigned int* data = (const unsigned int*)(S + (size_t)b * Ln * Ln);
    if (t == 0) { prefix_s = 0u; kk = (nedges[b] + 1) >> 1; } // ceil(n*0.5)
    for (int pass = 0; pass < 4; ++pass) {
        int shift = 24 - 8 * pass;
        for (int i = t; i < 16 * 256; i += 1024) ((unsigned int*)hist)[i] = 0u;
        __syncthreads();                 // hist zeroed; prefix_s/kk visible
        unsigned int pmask = (pass == 0) ? 0u : (0xFFFFFFFFu << (shift + 8));
        unsigned int pref = prefix_s;
        for (int i = t; i < Ln * Ln; i += 1024) {
            unsigned int x = data[i];
            if ((x & pmask) == pref) atomicAdd(&hist[wv][(x >> shift) & 255u], 1u);
        }
        __syncthreads();
        if (t < 256) {
            unsigned int s = 0;
            #pragma unroll
            for (int w = 0; w < 16; ++w) s += hist[w][t];
            comb[t] = s;
        }
        __syncthreads();
        // suffix-inclusive scan: comb[t] = sum_{i>=t} c[i]
        for (int off = 1; off < 256; off <<= 1) {
            unsigned int v = 0;
            if (t < 256) v = (t + off < 256) ? comb[t + off] : 0u;
            __syncthreads();
            if (t < 256) comb[t] += v;
            __syncthreads();
        }
        int kcur = kk;                   // all threads read before any write
        unsigned int Sself = (t < 256) ? comb[t] : 0u;
        unsigned int Snext = (t < 255) ? comb[t + 1] : 0u;
        __syncthreads();
        if (t < 256) {
            // pick largest bin b with S[b+1] <= k < S[b]  (same as serial desc scan)
            if ((unsigned int)kcur < Sself && (unsigned int)kcur >= Snext) {
                prefix_s = pref | ((unsigned int)t << shift);
                kk = kcur - (int)Snext;
            }
        }
        __syncthreads();
    }
    if (t == 0) thrA[b] = __uint_as_float(prefix_s);
}

// ---------------- degree -> dis = rsqrt(deg) ----------------
__global__ void deg_kernel(const float* S, const float* thrA, float* dis) {
    int l = blockIdx.x, b = blockIdx.y, t = threadIdx.x; // 64
    __shared__ float red[64];
    float thr = thrA[b];
    const float* row = S + ((size_t)b * Ln + l) * Ln;
    int cnt = 0;
    for (int m = t; m < Ln; m += 64) if (m != l && row[m] > thr) cnt++;
    red[t] = (float)cnt; __syncthreads();
    for (int s = 32; s > 0; s >>= 1) { if (t < s) red[t] += red[t + s]; __syncthreads(); }
    if (t == 0) dis[b * Ln + l] = rsqrtf(red[0] + 1.f); // +1 self loop
}

// ---------------- An = A_bool * dis_l * dis_m (in-place over S) ----------------
__global__ void an_kernel(float* S, const float* thrA, const float* dis) {
    size_t idx = (size_t)blockIdx.x * 256 + threadIdx.x;
    if (idx >= (size_t)Bn * Ln * Ln) return;
    int b = (int)(idx / (Ln * Ln));
    int rem = (int)(idx % (Ln * Ln));
    int l = rem / Ln, m = rem % Ln;
    float ab = (l == m) ? 1.f : ((S[idx] > thrA[b]) ? 1.f : 0.f);
    S[idx] = ab * dis[b * Ln + l] * dis[b * Ln + m];
}

// ---------------- C = An @ M per batch (M staged in LDS), 512 threads ----------------
__global__ __launch_bounds__(512) void an_mm2_kernel(const float* An, const float* M, float* C) {
    int b = blockIdx.x, t = threadIdx.x;
    __shared__ float Ml[200 * 128];    // 102.4 KB
    __shared__ float At[16 * 200];     // 12.8 KB
    const float4* src = (const float4*)(M + (size_t)b * Ln * Dn);
    for (int i = t; i < 6400; i += 512) ((float4*)Ml)[i] = src[i];
    int d0 = t & 63, rg = t >> 6;      // rg 0..7, rows rg*2..+1 within tile
    for (int rb = 0; rb < 13; ++rb) {
        int base = rb * 16;
        int nrows = (base + 16 <= Ln) ? 16 : (Ln - base);
        __syncthreads();               // protect At (and Ml on first iter)
        for (int i = t; i < nrows * 200; i += 512)
            At[i] = An[((size_t)b * Ln + base + i / 200) * Ln + (i % 200)];
        __syncthreads();
        if (rg * 2 < nrows) {
            float acc[2][2] = {{0,0},{0,0}};
            for (int m = 0; m < Ln; ++m) {
                float w0 = Ml[m * 128 + d0];
                float w1 = Ml[m * 128 + d0 + 64];
                #pragma unroll
                for (int ii = 0; ii < 2; ++ii) {
                    float a = At[(rg * 2 + ii) * 200 + m];
                    acc[ii][0] += a * w0;
                    acc[ii][1] += a * w1;
                }
            }
            #pragma unroll
            for (int ii = 0; ii < 2; ++ii) {
                if (rg * 2 + ii < nrows) {
                    size_t orow = (size_t)b * Ln + base + rg * 2 + ii;
                    C[orow * 128 + d0] = acc[ii][0];
                    C[orow * 128 + d0 + 64] = acc[ii][1];
                }
            }
        }
    }
}

// ---------------- out = in @ W128 (+ optional residual & leaky relu) ----------------
template<int RES>
__global__ __launch_bounds__(512) void ai2_kernel(const float* in, const float* Wm,
                                                  float* out, const float* res) {
    __shared__ float Wl[128 * 128];    // 64 KB
    __shared__ float Rl[128 * 128];    // 64 KB
    int t = threadIdx.x;
    size_t row0 = (size_t)blockIdx.x * 128;
    const float4* wsrc = (const float4*)Wm;
    for (int i = t; i < 4096; i += 512) ((float4*)Wl)[i] = wsrc[i];
    const float4* rsrc = (const float4*)(in + row0 * 128);
    for (int i = t; i < 4096; i += 512) ((float4*)Rl)[i] = rsrc[i];
    __syncthreads();
    int d0 = t & 63, rg = t >> 6;      // 8 groups of 16 rows
    float acc[16][2];
    #pragma unroll
    for (int rr = 0; rr < 16; ++rr) { acc[rr][0] = 0.f; acc[rr][1] = 0.f; }
    for (int k = 0; k < 128; ++k) {
        float w0 = Wl[k * 128 + d0], w1 = Wl[k * 128 + d0 + 64];
        #pragma unroll
        for (int rr = 0; rr < 16; ++rr) {
            float x = Rl[(rg * 16 + rr) * 128 + k];
            acc[rr][0] += x * w0;
            acc[rr][1] += x * w1;
        }
    }
    #pragma unroll
    for (int rr = 0; rr < 16; ++rr) {
        size_t orow = row0 + rg * 16 + rr;
        float v0 = acc[rr][0], v1 = acc[rr][1];
        if (RES) {
            v0 = lrelu(v0 + res[orow * 128 + d0]);
            v1 = lrelu(v1 + res[orow * 128 + d0 + 64]);
        }
        out[orow * 128 + d0] = v0;
        out[orow * 128 + d0 + 64] = v1;
    }
}

// ---------------- attn fc0: z0 = [ai,q,ai-q,ai*q] @ w0 + b0, fused BN stats ----------------
__global__ __launch_bounds__(256) void fc02_kernel(const float* ai, const float* query, int q3d,
                                                   const float* w0, const float* b0,
                                                   float* z0, float* stats0) {
    __shared__ float F[64 * 129];      // 33 KB feature chunk (padded)
    __shared__ float W[128 * 80];      // 40 KB weight chunk
    __shared__ float sums[160];
    int t = threadIdx.x;
    size_t row0 = (size_t)blockIdx.x * 64;
    float areg[32], qreg[32];
    #pragma unroll
    for (int j = 0; j < 32; ++j) {
        int i = t + j * 256;
        int r = i >> 7, k = i & 127;
        size_t grow = row0 + r;
        areg[j] = ai[grow * 128 + k];
        qreg[j] = q3d ? query[grow * 128 + k] : query[(grow / Ln) * 128 + k];
    }
    int r0 = (t & 31) * 2, cg = t >> 5;  // cols cg*10 + j
    float acc[2][10];
    #pragma unroll
    for (int j = 0; j < 10; ++j) { acc[0][j] = 0.f; acc[1][j] = 0.f; }
    for (int c = 0; c < 4; ++c) {
        if (c) __syncthreads();          // previous chunk's readers done
        #pragma unroll
        for (int j = 0; j < 32; ++j) {
            int i = t + j * 256;
            int r = i >> 7, k = i & 127;
            float a = areg[j], q = qreg[j];
            float f = (c == 0) ? a : (c == 1) ? q : (c == 2) ? (a - q) : (a * q);
            F[r * 129 + k] = f;
        }
        for (int i = t; i < 10240; i += 256) W[i] = w0[c * 10240 + i];
        __syncthreads();
        for (int k = 0; k < 128; ++k) {
            float f0 = F[r0 * 129 + k], f1v = F[(r0 + 1) * 129 + k];
            #pragma unroll
            for (int j = 0; j < 10; ++j) {
                float w = W[k * 80 + cg * 10 + j];
                acc[0][j] += f0 * w;
                acc[1][j] += f1v * w;
            }
        }
    }
    __syncthreads();
    if (t < 160) sums[t] = 0.f;
    __syncthreads();
    #pragma unroll
    for (int j = 0; j < 10; ++j) {
        float bb = b0[cg * 10 + j];
        float z0v = acc[0][j] + bb;
        float z1v = acc[1][j] + bb;
        z0[(row0 + r0) * 80 + cg * 10 + j] = z0v;
        z0[(row0 + r0 + 1) * 80 + cg * 10 + j] = z1v;
        atomicAdd(&sums[cg * 10 + j], z0v + z1v);
        atomicAdd(&sums[80 + cg * 10 + j], z0v * z0v + z1v * z1v);
    }
    __syncthreads();
    if (t < 80) {
        atomicAdd(&stats0[t], sums[t]);
        atomicAdd(&stats0[80 + t], sums[80 + t]);
    }
}

// ---------------- attn fc1: BN(z0)->relu -> @w1 + b1, fused BN stats ----------------
__global__ __launch_bounds__(256) void fc1b_kernel(const float* z0, const float* stats0,
                                                   const float* g0, const float* be0,
                                                   const float* w1, const float* b1,
                                                   float* z1, float* stats1, int N) {
    __shared__ float Y[64 * 81];
    __shared__ float W1s[80 * 40];
    __shared__ float mnA[80], rsA[80], gA[80], beA[80];
    __shared__ float sums[80];
    int t = threadIdx.x;
    size_t row0 = (size_t)blockIdx.x * 64;
    if (t < 80) {
        float mean = stats0[t] / N;
        float var = stats0[80 + t] / N - mean * mean;
        mnA[t] = mean; rsA[t] = rsqrtf(var + EPS); gA[t] = g0[t]; beA[t] = be0[t];
    }
    for (int i = t; i < 3200; i += 256) W1s[i] = w1[i];
    __syncthreads();
    for (int i = t; i < 5120; i += 256) {
        int r = i / 80, k = i % 80;
        float v = z0[row0 * 80 + i];
        float y = (v - mnA[k]) * rsA[k] * gA[k] + beA[k];
        Y[r * 81 + k] = fmaxf(y, 0.f);
    }
    __syncthreads();
    int r0 = (t & 31) * 2, cg = t >> 5;  // cols cg*5 + j
    float acc[2][5];
    #pragma unroll
    for (int j = 0; j < 5; ++j) { acc[0][j] = 0.f; acc[1][j] = 0.f; }
    for (int k = 0; k < 80; ++k) {
        float y0 = Y[r0 * 81 + k], y1 = Y[(r0 + 1) * 81 + k];
        #pragma unroll
        for (int j = 0; j < 5; ++j) {
            float w = W1s[k * 40 + cg * 5 + j];
            acc[0][j] += y0 * w;
            acc[1][j] += y1 * w;
        }
    }
    __syncthreads();
    if (t < 80) sums[t] = 0.f;
    __syncthreads();
    #pragma unroll
    for (int j = 0; j < 5; ++j) {
        float bb = b1[cg * 5 + j];
        float z0v = acc[0][j] + bb;
        float z1v = acc[1][j] + bb;
        z1[(row0 + r0) * 40 + cg * 5 + j] = z0v;
        z1[(row0 + r0 + 1) * 40 + cg * 5 + j] = z1v;
        atomicAdd(&sums[cg * 5 + j], z0v + z1v);
        atomicAdd(&sums[40 + cg * 5 + j], z0v * z0v + z1v * z1v);
    }
    __syncthreads();
    if (t < 40) {
        atomicAdd(&stats1[t], sums[t]);
        atomicAdd(&stats1[40 + t], sums[40 + t]);
    }
}

// ---------------- attn out: o = relu(BN(z1)) @ wo + bo ----------------
__global__ __launch_bounds__(256) void out2_kernel(const float* z1, const float* stats1,
                                                   const float* g1, const float* be1,
                                                   const float* wo, const float* bo,
                                                   float* o, int N) {
    __shared__ float Zs[256 * 41];
    __shared__ float mnA[40], rsA[40], gA[40], beA[40], woA[40];
    int t = threadIdx.x;
    size_t row0 = (size_t)blockIdx.x * 256;
    if (t < 40) {
        float mean = stats1[t] / N;
        float var = stats1[40 + t] / N - mean * mean;
        mnA[t] = mean; rsA[t] = rsqrtf(var + EPS);
        gA[t] = g1[t]; beA[t] = be1[t]; woA[t] = wo[t];
    }
    __syncthreads();
    for (int i = t; i < 10240; i += 256) {
        int r = i / 40, k = i % 40;
        float v = z1[row0 * 40 + i];
        float y = (v - mnA[k]) * rsA[k] * gA[k] + beA[k];
        Zs[r * 41 + k] = fmaxf(y, 0.f);
    }
    __syncthreads();
    float acc = bo[0];
    for (int k = 0; k < 40; ++k) acc += Zs[t * 41 + k] * woA[k];
    o[row0 + t] = acc;
}

// softmax over L with mask; optional second addend; optional *mask on output
__global__ void masked_softmax_kernel(const float* o, const float* o2, const float* mask,
                                      float neg, int mulmask, float* w) {
    int b = blockIdx.x, t = threadIdx.x; // 256
    __shared__ float buf[Ln];
    __shared__ float red[256];
    if (t < Ln) {
        float x = o[b * Ln + t];
        if (o2) x += o2[b * Ln + t];
        buf[t] = (mask[b * Ln + t] > 0.f) ? x : neg;
    }
    __syncthreads();
    red[t] = (t < Ln) ? buf[t] : -3.4e38f;
    __syncthreads();
    for (int s = 128; s > 0; s >>= 1) { if (t < s) red[t] = fmaxf(red[t], red[t + s]); __syncthreads(); }
    float mx = red[0];
    __syncthreads();
    float e = 0.f;
    if (t < Ln) e = expf(buf[t] - mx);
    red[t] = e;
    __syncthreads();
    for (int s = 128; s > 0; s >>= 1) { if (t < s) red[t] += red[t + s]; __syncthreads(); }
    float sm = red[0];
    if (t < Ln) {
        float v = e / sm;
        if (mulmask) v *= mask[b * Ln + t];
        w[b * Ln + t] = v;
    }
}

// ---------------- E row-softmax + ex = P @ X (per batch), 1024 threads ----------------
__global__ __launch_bounds__(1024) void fxc_p_kernel(const float* An, const float* f1, const float* f2,
                                                     const float* X, float* ex) {
    __shared__ float Xl[200 * 128];    // 102.4 KB
    __shared__ float p[16][200];       // 12.8 KB
    __shared__ float invs[16];
    __shared__ float f1s[200];
    int b = blockIdx.x, t = threadIdx.x;
    const float4* src = (const float4*)(X + (size_t)b * Ln * Dn);
    for (int i = t; i < 6400; i += 1024) ((float4*)Xl)[i] = src[i];
    for (int i = t; i < 200; i += 1024) f1s[i] = f1[b * Ln + i];
    __syncthreads();
    int wv = t >> 6, lane = t & 63;    // 16 waves
    for (int l0 = 0; l0 < Ln; l0 += 16) {
        int l = l0 + wv;
        bool act = (l < Ln);
        float f2l = act ? f2[b * Ln + l] : 0.f;
        const float* Arow = An + ((size_t)b * Ln + (act ? l : 0)) * Ln;
        float e[4]; float mx = -3.4e38f;
        #pragma unroll
        for (int j = 0; j < 4; ++j) {
            int m = lane + 64 * j;
            float ev = NEGINF;
            if (m < Ln) {
                float ab = Arow[m];
                if (ab > 0.f) { float s = f1s[m] + f2l; ev = (s > 0.f) ? s : 0.01f * s; }
            }
            e[j] = ev; mx = fmaxf(mx, ev);
        }
        for (int off = 32; off > 0; off >>= 1) mx = fmaxf(mx, __shfl_xor(mx, off));
        float sm = 0.f;
        #pragma unroll
        for (int j = 0; j < 4; ++j) {
            int m = lane + 64 * j;
            float pe = (m < Ln) ? expf(e[j] - mx) : 0.f;
            if (m < Ln) p[wv][m] = pe;
            sm += pe;
        }
        for (int off = 32; off > 0; off >>= 1) sm += __shfl_xor(sm, off);
        if (lane == 0) invs[wv] = 1.f / sm;
        __syncthreads();
        if (act) {
            int d0 = lane * 2;
            float a0 = 0.f, a1 = 0.f;
            const float* pr = p[wv];
            for (int m = 0; m < Ln; ++m) {
                float pm = pr[m];
                float2 x2 = *(const float2*)&Xl[m * 128 + d0];
                a0 += pm * x2.x;
                a1 += pm * x2.y;
            }
            float inv = invs[wv];
            size_t orow = (size_t)b * Ln + l;
            ex[orow * 128 + d0] = a0 * inv;
            ex[orow * 128 + d0 + 1] = a1 * inv;
        }
        __syncthreads();
    }
}

// ---------------- pooling: mask2 = cs > (k-th largest), order, red_len ----------------
__global__ void pool_kernel(const float* cs, const int* his_len, float* mask2,
                            int* order, int* red_len) {
    int b = blockIdx.x, t = threadIdx.x; // 256
    __shared__ float v[Ln];
    __shared__ float thr;
    if (t < Ln) v[t] = cs[b * Ln + t];
    __syncthreads();
    int k = min(his_len[b], POOLN);
    if (t < Ln) {
        float x = v[t];
        int gt = 0, eq = 0;
        for (int i = 0; i < Ln; ++i) { gt += (v[i] > x); eq += (v[i] == x); }
        if (gt <= k && k < gt + eq) thr = x; // the k-th order statistic (desc)
    }
    __syncthreads();
    if (t < Ln) mask2[b * Ln + t] = (v[t] > thr) ? 1.f : 0.f;
    __syncthreads();
    if (t == 0) {
        int idx = 0;
        for (int l = 0; l < Ln; ++l) if (v[l] > thr) order[b * Ln + idx++] = l;
        red_len[b] = idx;
        for (int l = 0; l < Ln; ++l) if (!(v[l] > thr)) order[b * Ln + idx++] = l;
    }
}

__global__ void readout_kernel(const float* Xc, const float* cs, const float* mask2, float* gr) {
    int b = blockIdx.x, t = threadIdx.x; // 128
    float acc = 0.f;
    for (int l = 0; l < Ln; ++l)
        acc += Xc[((size_t)b * Ln + l) * Dn + t] * cs[b * Ln + l] * mask2[b * Ln + l];
    gr[b * Dn + t] = acc;
}

__global__ void gather_kernel(const float* Xc, const float* mask2, const int* order,
                              float* Xs, float* mask_s) {
    int i = blockIdx.x, b = blockIdx.y, t = threadIdx.x; // 128
    int src = order[b * Ln + i];
    Xs[((size_t)b * Ln + i) * Dn + t] = Xc[((size_t)b * Ln + src) * Dn + t];
    if (t == 0) mask_s[b * Ln + i] = mask2[b * Ln + src];
}

// ---------------- AUGRU ----------------
__global__ void xp_kernel(const float* Xs, const float* Wx, const float* bx, float* xp) {
    int l = blockIdx.x, b = blockIdx.y, t = threadIdx.x; // 384
    __shared__ float x[Dn];
    if (t < Dn) x[t] = Xs[((size_t)b * Ln + l) * Dn + t];
    __syncthreads();
    float acc = bx[t];
    for (int d = 0; d < Dn; ++d) acc += x[d] * Wx[d * 384 + t];
    xp[((size_t)b * POOLN + l) * 384 + t] = acc;
}

__global__ void augru_kernel(const float* xp, const float* alphas, const int* red_len,
                             const float* Wh, const float* bh, float* final_h) {
    int b = blockIdx.x, j = threadIdx.x; // 128
    __shared__ float h[Hn];
    h[j] = 0.f;
    __syncthreads();
    int T = red_len[b];
    for (int step = 0; step < T; ++step) {
        float hr = bh[j], hu = bh[Hn + j], hn = bh[2 * Hn + j];
        for (int k = 0; k < Hn; ++k) {
            float hk = h[k];
            hr += hk * Wh[k * 384 + j];
            hu += hk * Wh[k * 384 + Hn + j];
            hn += hk * Wh[k * 384 + 2 * Hn + j];
        }
        const float* xrow = xp + ((size_t)b * POOLN + step) * 384;
        float a = alphas[b * Ln + step];
        float r = sigmoidf(xrow[j] + hr);
        float u = sigmoidf(xrow[Hn + j] + hu) * a;
        float n = tanhf(xrow[2 * Hn + j] + r * hn);
        float hnew = (1.f - u) * h[j] + u * n;
        __syncthreads();
        h[j] = hnew;
        __syncthreads();
    }
    final_h[b * Hn + j] = h[j];
}

// ---------------- head ----------------
__global__ void mo_kernel(const float* final_h, const float* gr, const float* tgt, float* mo) {
    int b = blockIdx.x, t = threadIdx.x; // 128
    mo[b * 512 + t] = final_h[b * Hn + t];
    mo[b * 512 + 128 + t] = gr[b * Dn + t];
    mo[b * 512 + 256 + t] = tgt[b * Dn + t];
    mo[b * 512 + 384 + t] = gr[b * Dn + t] * tgt[b * Dn + t];
}

// stats[c] = sum, stats[C+c] = sumsq.  blockDim=(C,TY)
__global__ void bn_stats_kernel(const float* z, int N, int C, float* stats) {
    int c = threadIdx.x;
    extern __shared__ float red[]; // 2*C*TY
    float s = 0.f, q = 0.f;
    for (int r = blockIdx.x * blockDim.y + threadIdx.y; r < N; r += gridDim.x * blockDim.y) {
        float v = z[(size_t)r * C + c];
        s += v; q += v * v;
    }
    red[threadIdx.y * C + c] = s;
    red[blockDim.y * C + threadIdx.y * C + c] = q;
    __syncthreads();
    if (threadIdx.y == 0) {
        for (int ty = 1; ty < (int)blockDim.y; ++ty) {
            s += red[ty * C + c];
            q += red[blockDim.y * C + ty * C + c];
        }
        atomicAdd(&stats[c], s);
        atomicAdd(&stats[C + c], q);
    }
}

// generic dense layer: optional BN+relu on input, then y = in' @ w + bias
__global__ void head_fc_kernel(const float* in, int K, int C, const float* w, const float* bias,
                               const float* stats, int statN, const float* g, const float* be,
                               float* out) {
    int b = blockIdx.x;
    extern __shared__ float y[]; // K floats
    for (int k = threadIdx.x; k < K; k += blockDim.x) {
        float v = in[(size_t)b * K + k];
        if (stats) {
            float mean = stats[k] / statN;
            float var = stats[K + k] / statN - mean * mean;
            v = fmaxf((v - mean) * rsqrtf(var + EPS) * g[k] + be[k], 0.f);
        }
        y[k] = v;
    }
    __syncthreads();
    for (int c = threadIdx.x; c < C; c += blockDim.x) {
        float acc = bias[c];
        for (int k = 0; k < K; ++k) acc += y[k] * w[k * C + c];
        out[(size_t)b * C + c] = acc;
    }
}

// ---------------- host driver ----------------
struct AttnParams {
    const float *w0, *b0, *g0, *be0, *w1, *b1, *g1, *be1, *wo, *bo;
};

static void run_attn_fcn(hipStream_t stream, const float* kv, const float* query, int q3d,
                         const float* mat, const float* mask, const AttnParams& P,
                         float* ai, float* z0, float* z1, float* o,
                         float* stats0, float* stats1, float* out_w) {
    ai2_kernel<0><<<400, 512, 0, stream>>>(kv, mat, ai, nullptr);
    hipMemsetAsync(stats0, 0, 160 * sizeof(float), stream);
    fc02_kernel<<<800, 256, 0, stream>>>(ai, query, q3d, P.w0, P.b0, z0, stats0);
    hipMemsetAsync(stats1, 0, 80 * sizeof(float), stream);
    fc1b_kernel<<<800, 256, 0, stream>>>(z0, stats0, P.g0, P.be0, P.w1, P.b1, z1, stats1, Bn * Ln);
    out2_kernel<<<200, 256, 0, stream>>>(z1, stats1, P.g1, P.be1, P.wo, P.bo, o, Bn * Ln);
    masked_softmax_kernel<<<Bn, 256, 0, stream>>>(o, nullptr, mask, NEGINF, 0, out_w);
}

extern "C" void kernel_launch(void* const* d_in, const int* in_sizes, int n_in,
                              void* d_out, int out_size, void* d_ws, size_t ws_size,
                              hipStream_t stream) {
    (void)in_sizes; (void)n_in; (void)out_size; (void)ws_size;
    const int* his_pro = (const int*)d_in[0];
    const int* his_y   = (const int*)d_in[1];
    const int* his_len = (const int*)d_in[2];
    const int* cur_pro = (const int*)d_in[3];
    const float* item_emb    = (const float*)d_in[5];
    const float* ans_emb     = (const float*)d_in[6];
    const float* wt          = (const float*)d_in[7];
    const float* att_cluster = (const float*)d_in[8];
    const float* att_query   = (const float*)d_in[9];
    const float* att_rnn     = (const float*)d_in[10];
    const float* aggre_W     = (const float*)d_in[11];
    const float* gru_Wx = (const float*)d_in[12];
    const float* gru_Wh = (const float*)d_in[13];
    const float* gru_bx = (const float*)d_in[14];
    const float* gru_bh = (const float*)d_in[15];
    AttnParams AP;
    AP.w0 = (const float*)d_in[16]; AP.b0 = (const float*)d_in[17];
    AP.g0 = (const float*)d_in[18]; AP.be0 = (const float*)d_in[19];
    AP.w1 = (const float*)d_in[20]; AP.b1 = (const float*)d_in[21];
    AP.g1 = (const float*)d_in[22]; AP.be1 = (const float*)d_in[23];
    AP.wo = (const float*)d_in[24]; AP.bo = (const float*)d_in[25];
    const float* t_w0 = (const float*)d_in[26];
    const float* t_b0 = (const float*)d_in[27];
    const float* t_g0 = (const float*)d_in[28];
    const float* t_be0 = (const float*)d_in[29];
    const float* t_w1 = (const float*)d_in[30];
    const float* t_b1 = (const float*)d_in[31];
    const float* t_g1 = (const float*)d_in[32];
    const float* t_be1 = (const float*)d_in[33];
    const float* t_wo = (const float*)d_in[34];
    const float* t_bo = (const float*)d_in[35];

    // -------- workspace carve --------
    char* p = (char*)d_ws;
    auto alloc = [&](size_t bytes) -> void* {
        void* r = (void*)p;
        p += ((bytes + 255) / 256) * 256;
        return r;
    };
    const size_t NX = (size_t)Bn * Ln * Dn;
    const size_t NS = (size_t)Bn * Ln * Ln;
    float* X    = (float*)alloc(NX * 4);
    float* XfXc = (float*)alloc(NX * 4);   // Xf, later reused as Xc
    float* S    = (float*)alloc(NS * 4);   // S raw -> scaled -> An in-place
    float* tmp  = (float*)alloc(NX * 4);   // An@M temp / attn 'ai' / ex
    float* XqXs = (float*)alloc(NX * 4);   // Xq, later Xs
    float* z0   = (float*)alloc((size_t)Bn * Ln * C0 * 4);
    float* z1   = (float*)alloc((size_t)Bn * Ln * C1 * 4);
    float* obuf = (float*)alloc((size_t)Bn * Ln * 4);
    float* f1   = (float*)alloc((size_t)Bn * Ln * 4);
    float* f2   = (float*)alloc((size_t)Bn * Ln * 4);
    float* alph = (float*)alloc((size_t)Bn * Ln * 4);
    float* mask = (float*)alloc((size_t)Bn * Ln * 4);
    float* tgt  = (float*)alloc((size_t)Bn * Dn * 4);
    float* dis  = (float*)alloc((size_t)Bn * Ln * 4);
    float* thrA = (float*)alloc((size_t)Bn * 4);
    int*   nedges = (int*)alloc((size_t)Bn * 4);
    float* rowmin = (float*)alloc((size_t)Bn * Ln * 4);
    float* rowmax = (float*)alloc((size_t)Bn * Ln * 4);
    float* statsA = (float*)alloc(2 * 200 * 4);
    float* statsB = (float*)alloc(2 * 200 * 4);
    float* cs     = (float*)alloc((size_t)Bn * Ln * 4);
    float* mask2  = (float*)alloc((size_t)Bn * Ln * 4);
    int*   order  = (int*)alloc((size_t)Bn * Ln * 4);
    int*   redlen = (int*)alloc((size_t)Bn * 4);
    float* mask_s = (float*)alloc((size_t)Bn * Ln * 4);
    float* xp     = (float*)alloc((size_t)Bn * POOLN * 384 * 4);
    float* finalh = (float*)alloc((size_t)Bn * Hn * 4);
    float* gr     = (float*)alloc((size_t)Bn * Dn * 4);
    float* mo     = (float*)alloc((size_t)Bn * 512 * 4);
    float* t0buf  = (float*)alloc((size_t)Bn * T0 * 4);
    float* t1buf  = (float*)alloc((size_t)Bn * T1 * 4);

    dim3 gLB(Ln, Bn);

    // ---- inputs ----
    build_x_kernel<<<gLB, 128, 0, stream>>>(his_pro, his_y, item_emb, ans_emb, X);
    build_tgt_mask_kernel<<<Bn, 256, 0, stream>>>(cur_pro, his_len, item_emb, tgt, mask);

    // ---- similarity graph ----
    xf_kernel<<<gLB, 128, 0, stream>>>(X, wt, XfXc);
    s2_gemm_kernel<<<Bn, 256, 0, stream>>>(XfXc, S, rowmin, rowmax);
    s2_scale_kernel<<<Bn, 256, 0, stream>>>(S, rowmin, rowmax, mask, nedges);
    radix_select2_kernel<<<Bn, 1024, 0, stream>>>(S, nedges, thrA);
    deg_kernel<<<gLB, 64, 0, stream>>>(S, thrA, dis);
    an_kernel<<<(int)((NS + 255) / 256), 256, 0, stream>>>(S, thrA, dis); // S -> An

    // ---- fusion round 1 ----
    an_mm2_kernel<<<Bn, 512, 0, stream>>>(S, X, tmp);
    an_mm2_kernel<<<Bn, 512, 0, stream>>>(S, tmp, XqXs); // Xq
    run_attn_fcn(stream, X, XqXs, 1, att_cluster, mask, AP, tmp, z0, z1, obuf, statsA, statsB, f1);
    run_attn_fcn(stream, X, tgt, 0, att_query, mask, AP, tmp, z0, z1, obuf, statsA, statsB, f2);
    fxc_p_kernel<<<Bn, 1024, 0, stream>>>(S, f1, f2, X, tmp);      // ex -> tmp
    ai2_kernel<1><<<400, 512, 0, stream>>>(tmp, aggre_W, XfXc, X); // Xc = lrelu(ex@W + X)

    // ---- fusion round 2 (extraction) ----
    an_mm2_kernel<<<Bn, 512, 0, stream>>>(S, XfXc, tmp);
    an_mm2_kernel<<<Bn, 512, 0, stream>>>(S, tmp, XqXs); // Xq2
    run_attn_fcn(stream, XfXc, XqXs, 1, att_cluster, mask, AP, tmp, z0, z1, obuf, statsA, statsB, f1);
    run_attn_fcn(stream, XfXc, tgt, 0, att_query, mask, AP, tmp, z0, z1, obuf, statsA, statsB, f2);
    masked_softmax_kernel<<<Bn, 256, 0, stream>>>(f1, f2, mask, NEGBIG, 1, cs);

    // ---- pooling ----
    pool_kernel<<<Bn, 256, 0, stream>>>(cs, his_len, mask2, order, redlen);
    readout_kernel<<<Bn, 128, 0, stream>>>(XfXc, cs, mask2, gr);
    gather_kernel<<<gLB, 128, 0, stream>>>(XfXc, mask2, order, XqXs, mask_s); // Xs

    // ---- AUGRU ----
    run_attn_fcn(stream, XqXs, tgt, 0, att_rnn, mask_s, AP, tmp, z0, z1, obuf, statsA, statsB, alph);
    xp_kernel<<<dim3(POOLN, Bn), 384, 0, stream>>>(XqXs, gru_Wx, gru_bx, xp);
    augru_kernel<<<Bn, 128, 0, stream>>>(xp, alph, redlen, gru_Wh, gru_bh, finalh);

    // ---- head ----
    mo_kernel<<<Bn, 128, 0, stream>>>(finalh, gr, tgt, mo);
    head_fc_kernel<<<Bn, 256, 512 * 4, stream>>>(mo, 512, T0, t_w0, t_b0,
                                                 nullptr, 0, nullptr, nullptr, t0buf);
    hipMemsetAsync(statsA, 0, 2 * T0 * sizeof(float), stream);
    bn_stats_kernel<<<32, dim3(T0, 1), 2 * T0 * sizeof(float), stream>>>(t0buf, Bn, T0, statsA);
    head_fc_kernel<<<Bn, 256, T0 * 4, stream>>>(t0buf, T0, T1, t_w1, t_b1,
                                                statsA, Bn, t_g0, t_be0, t1buf);
    hipMemsetAsync(statsB, 0, 2 * T1 * sizeof(float), stream);
    bn_stats_kernel<<<16, dim3(T1, 3), 2 * T1 * 3 * sizeof(float), stream>>>(t1buf, Bn, T1, statsB);
    head_fc_kernel<<<Bn, 256, T1 * 4, stream>>>(t1buf, T1, 1, t_wo, t_bo,
                                                statsB, Bn, t_g1, t_be1, (float*)d_out);
}